// Round 1
// baseline (896.873 us; speedup 1.0000x reference)
//
#include <hip/hip_runtime.h>

#define BB 4
#define NN 10000
#define EE 320000
#define HH 128

// ---------------------------------------------------------------------------
// 1) degree (float sum of edge weights into col) + count (int, for CSR)
// ---------------------------------------------------------------------------
__global__ __launch_bounds__(256) void deg_count_kernel(
    const int* __restrict__ edges, const float* __restrict__ attr,
    float* __restrict__ deg, int* __restrict__ cnt) {
  int b = blockIdx.y;
  int e = blockIdx.x * 256 + threadIdx.x;
  if (e >= EE) return;
  int col = edges[(size_t)b * 2 * EE + EE + e];
  float w = attr[(size_t)b * EE + e];
  atomicAdd(&deg[b * NN + col], w);
  atomicAdd(&cnt[b * NN + col], 1);
}

// ---------------------------------------------------------------------------
// 2) exclusive prefix sum of cnt -> rowstart (one block per graph)
// ---------------------------------------------------------------------------
__global__ __launch_bounds__(256) void scan_kernel(
    const int* __restrict__ cnt, int* __restrict__ rowstart) {
  int b = blockIdx.x;
  int t = threadIdx.x;
  __shared__ int s[256];
  int running = 0;
  for (int base = 0; base < NN; base += 256) {
    int i = base + t;
    int v = (i < NN) ? cnt[b * NN + i] : 0;
    s[t] = v;
    __syncthreads();
    for (int o = 1; o < 256; o <<= 1) {
      int add = (t >= o) ? s[t - o] : 0;
      __syncthreads();
      s[t] += add;
      __syncthreads();
    }
    if (i < NN) rowstart[b * (NN + 1) + i] = running + s[t] - v;
    int tot = s[255];
    __syncthreads();
    running += tot;
  }
  if (t == 0) rowstart[b * (NN + 1) + NN] = running;
}

// ---------------------------------------------------------------------------
// 3) fill CSR: src row index + fused gcn norm (dinv[row]*w*dinv[col])
// ---------------------------------------------------------------------------
__global__ __launch_bounds__(256) void fill_kernel(
    const int* __restrict__ edges, const float* __restrict__ attr,
    const float* __restrict__ deg, const int* __restrict__ rowstart,
    int* __restrict__ cur, int* __restrict__ csr_row, float* __restrict__ csr_nrm) {
  int b = blockIdx.y;
  int e = blockIdx.x * 256 + threadIdx.x;
  if (e >= EE) return;
  int row = edges[(size_t)b * 2 * EE + e];
  int col = edges[(size_t)b * 2 * EE + EE + e];
  float w = attr[(size_t)b * EE + e];
  float dr = deg[b * NN + row];
  float dc = deg[b * NN + col];
  float dir_ = dr > 0.f ? rsqrtf(dr) : 0.f;
  float dic_ = dc > 0.f ? rsqrtf(dc) : 0.f;
  int pos = rowstart[b * (NN + 1) + col] + atomicAdd(&cur[b * NN + col], 1);
  csr_row[(size_t)b * EE + pos] = row;
  csr_nrm[(size_t)b * EE + pos] = dir_ * w * dic_;
}

// ---------------------------------------------------------------------------
// 4) dense GEMM: out[b,n,:] = x[b,n,:] @ W   (x already post-activation)
//    16 rows x 128 cols per block; thread = (row r of 16, col-group of 8)
// ---------------------------------------------------------------------------
__global__ __launch_bounds__(256) void gemm_kernel(
    const float* __restrict__ x, const float* __restrict__ W,
    float* __restrict__ out) {
  int b = blockIdx.y;
  int row0 = blockIdx.x * 16;
  int t = threadIdx.x;
  __shared__ float xs[16 * 128];
  const float* xg = x + ((size_t)b * NN + row0) * 128;
#pragma unroll
  for (int i = 0; i < 2; ++i) {
    int idx = t + i * 256;  // 512 float4 total
    ((float4*)xs)[idx] = ((const float4*)xg)[idx];
  }
  __syncthreads();
  int r = t >> 4;           // 16 rows
  int c0 = (t & 15) * 8;    // 16 col-groups of 8
  float acc[8] = {0, 0, 0, 0, 0, 0, 0, 0};
#pragma unroll 4
  for (int k = 0; k < 128; ++k) {
    float xv = xs[r * 128 + k];
    const float4* wp = (const float4*)(W + k * 128 + c0);
    float4 w0 = wp[0];
    float4 w1 = wp[1];
    acc[0] += xv * w0.x; acc[1] += xv * w0.y; acc[2] += xv * w0.z; acc[3] += xv * w0.w;
    acc[4] += xv * w1.x; acc[5] += xv * w1.y; acc[6] += xv * w1.z; acc[7] += xv * w1.w;
  }
  float* og = out + ((size_t)b * NN + row0 + r) * 128 + c0;
  ((float4*)og)[0] = make_float4(acc[0], acc[1], acc[2], acc[3]);
  ((float4*)og)[1] = make_float4(acc[4], acc[5], acc[6], acc[7]);
}

// ---------------------------------------------------------------------------
// 5) CSR gather-aggregate + bias + ReLU: one wave per destination node,
//    lane owns 2 features (float2). h[b,n,f] = relu(sum norm*xw[src,f] + bias)
// ---------------------------------------------------------------------------
__global__ __launch_bounds__(256) void agg_kernel(
    const float* __restrict__ xw, const int* __restrict__ csr_row,
    const float* __restrict__ csr_nrm, const int* __restrict__ rowstart,
    const float* __restrict__ bias, float* __restrict__ h) {
  int b = blockIdx.y;
  int n = blockIdx.x * 4 + (threadIdx.x >> 6);
  int lane = threadIdx.x & 63;
  int s0 = rowstart[b * (NN + 1) + n];
  int s1 = rowstart[b * (NN + 1) + n + 1];
  const float* xwg = xw + (size_t)b * NN * 128;
  const int* rows = csr_row + (size_t)b * EE;
  const float* nrms = csr_nrm + (size_t)b * EE;
  float ax = 0.f, ay = 0.f;
  for (int i = s0; i < s1; ++i) {
    int r = rows[i];
    float w = nrms[i];
    float2 v = *(const float2*)(xwg + (size_t)r * 128 + lane * 2);
    ax += w * v.x;
    ay += w * v.y;
  }
  float2 bb = *(const float2*)(bias + lane * 2);
  float ox = fmaxf(ax + bb.x, 0.f);
  float oy = fmaxf(ay + bb.y, 0.f);
  *(float2*)(h + ((size_t)b * NN + n) * 128 + lane * 2) = make_float2(ox, oy);
}

// ---------------------------------------------------------------------------
// 6) readout: out[b] = mean_n(h3[b,n,:]) @ Wl + bl
// ---------------------------------------------------------------------------
__global__ __launch_bounds__(64) void init_out_kernel(float* out, const float* __restrict__ bl) {
  if (threadIdx.x < BB) out[threadIdx.x] = bl[0];
}

__global__ __launch_bounds__(256) void final_kernel(
    const float* __restrict__ h, const float* __restrict__ Wl,
    float* __restrict__ out) {
  int b = blockIdx.y;
  int t = threadIdx.x;
  int f = t & 127;
  int rr = t >> 7;
  float p = 0.f;
  for (int n = blockIdx.x * 2 + rr; n < NN; n += gridDim.x * 2)
    p += h[((size_t)b * NN + n) * 128 + f];
  __shared__ float s[256];
  s[t] = p;
  __syncthreads();
  float v = 0.f;
  if (t < 128) v = (s[t] + s[t + 128]) * Wl[f];
  __syncthreads();
  s[t] = v;
  __syncthreads();
  for (int o = 64; o > 0; o >>= 1) {
    if (t < o) s[t] += s[t + o];
    __syncthreads();
  }
  if (t == 0) atomicAdd(&out[b], s[0] * (1.0f / NN));
}

// ---------------------------------------------------------------------------
extern "C" void kernel_launch(void* const* d_in, const int* in_sizes, int n_in,
                              void* d_out, int out_size, void* d_ws, size_t ws_size,
                              hipStream_t stream) {
  const float* feat = (const float*)d_in[0];
  const int* edges = (const int*)d_in[1];
  const float* attr = (const float*)d_in[2];
  const float* W1 = (const float*)d_in[3];
  const float* b1 = (const float*)d_in[4];
  const float* W2 = (const float*)d_in[5];
  const float* b2 = (const float*)d_in[6];
  const float* W3 = (const float*)d_in[7];
  const float* b3 = (const float*)d_in[8];
  const float* Wl = (const float*)d_in[9];
  const float* bl = (const float*)d_in[10];
  float* out = (float*)d_out;

  char* ws = (char*)d_ws;
  size_t off = 0;
  auto alloc = [&](size_t bytes) {
    size_t o = off;
    off = (off + bytes + 255) & ~(size_t)255;
    return o;
  };
  float* deg     = (float*)(ws + alloc((size_t)BB * NN * 4));
  int*   cnt     = (int*)  (ws + alloc((size_t)BB * NN * 4));
  int*   cur     = (int*)  (ws + alloc((size_t)BB * NN * 4));
  int*   rowstart= (int*)  (ws + alloc((size_t)BB * (NN + 1) * 4));
  int*   csr_row = (int*)  (ws + alloc((size_t)BB * EE * 4));
  float* csr_nrm = (float*)(ws + alloc((size_t)BB * EE * 4));
  float* xw      = (float*)(ws + alloc((size_t)BB * NN * HH * 4));
  float* h       = (float*)(ws + alloc((size_t)BB * NN * HH * 4));

  // zero deg + cnt + cur (contiguous, 3 * 160000 bytes)
  hipMemsetAsync(deg, 0, (size_t)3 * BB * NN * 4, stream);

  dim3 egrid(EE / 256, BB);
  deg_count_kernel<<<egrid, 256, 0, stream>>>(edges, attr, deg, cnt);
  scan_kernel<<<BB, 256, 0, stream>>>(cnt, rowstart);
  fill_kernel<<<egrid, 256, 0, stream>>>(edges, attr, deg, rowstart, cur, csr_row, csr_nrm);

  dim3 ggrid(NN / 16, BB);
  dim3 agrid(NN / 4, BB);

  // layer 1
  gemm_kernel<<<ggrid, 256, 0, stream>>>(feat, W1, xw);
  agg_kernel<<<agrid, 256, 0, stream>>>(xw, csr_row, csr_nrm, rowstart, b1, h);
  // layer 2
  gemm_kernel<<<ggrid, 256, 0, stream>>>(h, W2, xw);
  agg_kernel<<<agrid, 256, 0, stream>>>(xw, csr_row, csr_nrm, rowstart, b2, h);
  // layer 3
  gemm_kernel<<<ggrid, 256, 0, stream>>>(h, W3, xw);
  agg_kernel<<<agrid, 256, 0, stream>>>(xw, csr_row, csr_nrm, rowstart, b3, h);

  init_out_kernel<<<1, 64, 0, stream>>>(out, bl);
  final_kernel<<<dim3(64, BB), 256, 0, stream>>>(h, Wl, out);
}

// Round 2
// 655.010 us; speedup vs baseline: 1.3693x; 1.3693x over previous
//
#include <hip/hip_runtime.h>

#define BB 4
#define NN 10000
#define EE 320000
#define HH 128

// ---------------------------------------------------------------------------
// 1) rank pass: rank[e] = slot of edge within its col segment; cnt = histogram
//    (the ONLY atomic pass in the whole pipeline)
// ---------------------------------------------------------------------------
__global__ __launch_bounds__(256) void rank_kernel(
    const int* __restrict__ edges, int* __restrict__ cnt,
    int* __restrict__ rank) {
  int b = blockIdx.y;
  int e = blockIdx.x * 256 + threadIdx.x;
  int col = edges[(size_t)b * 2 * EE + EE + e];
  rank[(size_t)b * EE + e] = atomicAdd(&cnt[b * NN + col], 1);
}

// ---------------------------------------------------------------------------
// 2) exclusive prefix sum of cnt -> rowstart (one block per graph)
// ---------------------------------------------------------------------------
__global__ __launch_bounds__(256) void scan_kernel(
    const int* __restrict__ cnt, int* __restrict__ rowstart) {
  int b = blockIdx.x;
  int t = threadIdx.x;
  __shared__ int s[256];
  int running = 0;
  for (int base = 0; base < NN; base += 256) {
    int i = base + t;
    int v = (i < NN) ? cnt[b * NN + i] : 0;
    s[t] = v;
    __syncthreads();
    for (int o = 1; o < 256; o <<= 1) {
      int add = (t >= o) ? s[t - o] : 0;
      __syncthreads();
      s[t] += add;
      __syncthreads();
    }
    if (i < NN) rowstart[b * (NN + 1) + i] = running + s[t] - v;
    int tot = s[255];
    __syncthreads();
    running += tot;
  }
  if (t == 0) rowstart[b * (NN + 1) + NN] = running;
}

// ---------------------------------------------------------------------------
// 3) fill CSR (no atomics): csr[pos] = {row, bits(w)}
// ---------------------------------------------------------------------------
__global__ __launch_bounds__(256) void fill_kernel(
    const int* __restrict__ edges, const float* __restrict__ attr,
    const int* __restrict__ rank, const int* __restrict__ rowstart,
    int2* __restrict__ csr) {
  int b = blockIdx.y;
  int e = blockIdx.x * 256 + threadIdx.x;
  int row = edges[(size_t)b * 2 * EE + e];
  int col = edges[(size_t)b * 2 * EE + EE + e];
  float w = attr[(size_t)b * EE + e];
  int pos = rowstart[b * (NN + 1) + col] + rank[(size_t)b * EE + e];
  csr[(size_t)b * EE + pos] = make_int2(row, __float_as_int(w));
}

// ---------------------------------------------------------------------------
// 4) deg/dinv: segment-sum of w (contiguous, no atomics) -> dinv = rsqrt
// ---------------------------------------------------------------------------
__global__ __launch_bounds__(256) void deg_kernel(
    const int2* __restrict__ csr, const int* __restrict__ rowstart,
    float* __restrict__ dinv) {
  int b = blockIdx.y;
  int n = blockIdx.x * 256 + threadIdx.x;
  if (n >= NN) return;
  int s0 = rowstart[b * (NN + 1) + n];
  int s1 = rowstart[b * (NN + 1) + n + 1];
  const int2* c = csr + (size_t)b * EE;
  float sum = 0.f;
  for (int i = s0; i < s1; ++i) sum += __int_as_float(c[i].y);
  dinv[b * NN + n] = sum > 0.f ? rsqrtf(sum) : 0.f;
}

// ---------------------------------------------------------------------------
// 5) normalize in place: csr[i].y = bits(dinv[col] * w * dinv[row])
//    one wave per destination node
// ---------------------------------------------------------------------------
__global__ __launch_bounds__(256) void norm_kernel(
    int2* __restrict__ csr, const int* __restrict__ rowstart,
    const float* __restrict__ dinv) {
  int b = blockIdx.y;
  int n = blockIdx.x * 4 + (threadIdx.x >> 6);
  int lane = threadIdx.x & 63;
  int s0 = rowstart[b * (NN + 1) + n];
  int s1 = rowstart[b * (NN + 1) + n + 1];
  float dc = dinv[b * NN + n];
  int2* c = csr + (size_t)b * EE;
  for (int i = s0 + lane; i < s1; i += 64) {
    int2 e = c[i];
    float nr = dc * __int_as_float(e.y) * dinv[b * NN + e.x];
    c[i].y = __float_as_int(nr);
  }
}

// ---------------------------------------------------------------------------
// 6) dense GEMM: out[b,n,:] = x[b,n,:] @ W
// ---------------------------------------------------------------------------
__global__ __launch_bounds__(256) void gemm_kernel(
    const float* __restrict__ x, const float* __restrict__ W,
    float* __restrict__ out) {
  int b = blockIdx.y;
  int row0 = blockIdx.x * 16;
  int t = threadIdx.x;
  __shared__ float xs[16 * 128];
  const float* xg = x + ((size_t)b * NN + row0) * 128;
#pragma unroll
  for (int i = 0; i < 2; ++i) {
    int idx = t + i * 256;
    ((float4*)xs)[idx] = ((const float4*)xg)[idx];
  }
  __syncthreads();
  int r = t >> 4;
  int c0 = (t & 15) * 8;
  float acc[8] = {0, 0, 0, 0, 0, 0, 0, 0};
#pragma unroll 4
  for (int k = 0; k < 128; ++k) {
    float xv = xs[r * 128 + k];
    const float4* wp = (const float4*)(W + k * 128 + c0);
    float4 w0 = wp[0];
    float4 w1 = wp[1];
    acc[0] += xv * w0.x; acc[1] += xv * w0.y; acc[2] += xv * w0.z; acc[3] += xv * w0.w;
    acc[4] += xv * w1.x; acc[5] += xv * w1.y; acc[6] += xv * w1.z; acc[7] += xv * w1.w;
  }
  float* og = out + ((size_t)b * NN + row0 + r) * 128 + c0;
  ((float4*)og)[0] = make_float4(acc[0], acc[1], acc[2], acc[3]);
  ((float4*)og)[1] = make_float4(acc[4], acc[5], acc[6], acc[7]);
}

// ---------------------------------------------------------------------------
// 7) CSR gather-aggregate + bias + ReLU, XCD-localized:
//    graph b's blocks land on XCDs {2b, 2b+1} (block->XCD is round-robin %8),
//    so each graph's 5.1MB xw stays in an 8MB L2 pair.
//    One wave per destination node; lane owns 2 features.
// ---------------------------------------------------------------------------
__global__ __launch_bounds__(256) void agg_kernel(
    const float* __restrict__ xw, const int2* __restrict__ csr,
    const int* __restrict__ rowstart, const float* __restrict__ bias,
    float* __restrict__ h) {
  int xcd = blockIdx.x & 7;
  int b = xcd >> 1;
  int chunk = ((blockIdx.x >> 3) << 1) + (xcd & 1);   // [0, 2500)
  int n = chunk * 4 + (threadIdx.x >> 6);
  int lane = threadIdx.x & 63;
  int s0 = rowstart[b * (NN + 1) + n];
  int s1 = rowstart[b * (NN + 1) + n + 1];
  const float* xwg = xw + (size_t)b * NN * 128;
  const int2* c = csr + (size_t)b * EE;
  float ax = 0.f, ay = 0.f, bx = 0.f, by = 0.f;
  int i = s0;
  for (; i + 2 <= s1; i += 2) {
    int2 e0 = c[i];
    int2 e1 = c[i + 1];
    float2 v0 = *(const float2*)(xwg + (size_t)e0.x * 128 + lane * 2);
    float2 v1 = *(const float2*)(xwg + (size_t)e1.x * 128 + lane * 2);
    float w0 = __int_as_float(e0.y);
    float w1 = __int_as_float(e1.y);
    ax += w0 * v0.x; ay += w0 * v0.y;
    bx += w1 * v1.x; by += w1 * v1.y;
  }
  if (i < s1) {
    int2 e0 = c[i];
    float2 v0 = *(const float2*)(xwg + (size_t)e0.x * 128 + lane * 2);
    float w0 = __int_as_float(e0.y);
    ax += w0 * v0.x; ay += w0 * v0.y;
  }
  ax += bx; ay += by;
  float2 bb = *(const float2*)(bias + lane * 2);
  float ox = fmaxf(ax + bb.x, 0.f);
  float oy = fmaxf(ay + bb.y, 0.f);
  *(float2*)(h + ((size_t)b * NN + n) * 128 + lane * 2) = make_float2(ox, oy);
}

// ---------------------------------------------------------------------------
// 8) readout: out[b] = mean_n(h3[b,n,:]) @ Wl + bl
// ---------------------------------------------------------------------------
__global__ __launch_bounds__(64) void init_out_kernel(float* out, const float* __restrict__ bl) {
  if (threadIdx.x < BB) out[threadIdx.x] = bl[0];
}

__global__ __launch_bounds__(256) void final_kernel(
    const float* __restrict__ h, const float* __restrict__ Wl,
    float* __restrict__ out) {
  int b = blockIdx.y;
  int t = threadIdx.x;
  int f = t & 127;
  int rr = t >> 7;
  float p = 0.f;
  for (int n = blockIdx.x * 2 + rr; n < NN; n += gridDim.x * 2)
    p += h[((size_t)b * NN + n) * 128 + f];
  __shared__ float s[256];
  s[t] = p;
  __syncthreads();
  float v = 0.f;
  if (t < 128) v = (s[t] + s[t + 128]) * Wl[f];
  __syncthreads();
  s[t] = v;
  __syncthreads();
  for (int o = 64; o > 0; o >>= 1) {
    if (t < o) s[t] += s[t + o];
    __syncthreads();
  }
  if (t == 0) atomicAdd(&out[b], s[0] * (1.0f / NN));
}

// ---------------------------------------------------------------------------
extern "C" void kernel_launch(void* const* d_in, const int* in_sizes, int n_in,
                              void* d_out, int out_size, void* d_ws, size_t ws_size,
                              hipStream_t stream) {
  const float* feat = (const float*)d_in[0];
  const int* edges = (const int*)d_in[1];
  const float* attr = (const float*)d_in[2];
  const float* W1 = (const float*)d_in[3];
  const float* b1 = (const float*)d_in[4];
  const float* W2 = (const float*)d_in[5];
  const float* b2 = (const float*)d_in[6];
  const float* W3 = (const float*)d_in[7];
  const float* b3 = (const float*)d_in[8];
  const float* Wl = (const float*)d_in[9];
  const float* bl = (const float*)d_in[10];
  float* out = (float*)d_out;

  char* ws = (char*)d_ws;
  size_t off = 0;
  auto alloc = [&](size_t bytes) {
    size_t o = off;
    off = (off + bytes + 255) & ~(size_t)255;
    return o;
  };
  int*   cnt     = (int*)  (ws + alloc((size_t)BB * NN * 4));
  int*   rank    = (int*)  (ws + alloc((size_t)BB * EE * 4));
  int*   rowstart= (int*)  (ws + alloc((size_t)BB * (NN + 1) * 4));
  int2*  csr     = (int2*) (ws + alloc((size_t)BB * EE * 8));
  float* dinv    = (float*)(ws + alloc((size_t)BB * NN * 4));
  float* xw      = (float*)(ws + alloc((size_t)BB * NN * HH * 4));
  float* h       = (float*)(ws + alloc((size_t)BB * NN * HH * 4));

  hipMemsetAsync(cnt, 0, (size_t)BB * NN * 4, stream);

  dim3 egrid(EE / 256, BB);
  rank_kernel<<<egrid, 256, 0, stream>>>(edges, cnt, rank);
  scan_kernel<<<BB, 256, 0, stream>>>(cnt, rowstart);
  fill_kernel<<<egrid, 256, 0, stream>>>(edges, attr, rank, rowstart, csr);
  deg_kernel<<<dim3((NN + 255) / 256, BB), 256, 0, stream>>>(csr, rowstart, dinv);
  norm_kernel<<<dim3(NN / 4, BB), 256, 0, stream>>>(csr, rowstart, dinv);

  dim3 ggrid(NN / 16, BB);
  int agrid = (NN / 4) * BB;  // flat, XCD-swizzled inside kernel

  // layer 1
  gemm_kernel<<<ggrid, 256, 0, stream>>>(feat, W1, xw);
  agg_kernel<<<agrid, 256, 0, stream>>>(xw, csr, rowstart, b1, h);
  // layer 2
  gemm_kernel<<<ggrid, 256, 0, stream>>>(h, W2, xw);
  agg_kernel<<<agrid, 256, 0, stream>>>(xw, csr, rowstart, b2, h);
  // layer 3
  gemm_kernel<<<ggrid, 256, 0, stream>>>(h, W3, xw);
  agg_kernel<<<agrid, 256, 0, stream>>>(xw, csr, rowstart, b3, h);

  init_out_kernel<<<1, 64, 0, stream>>>(out, bl);
  final_kernel<<<dim3(64, BB), 256, 0, stream>>>(h, Wl, out);
}

// Round 9
// 467.674 us; speedup vs baseline: 1.9177x; 1.4006x over previous
//
#include <hip/hip_runtime.h>

#define BB 4
#define NN 10000
#define EE 320000
#define HH 128
#define HALFN 5000
#define NK2 (2 * NN)       // CSR keys per graph: (srcHalf, col)
#define RS (2 * NN + 1)

// ---------------------------------------------------------------------------
// 1) rank pass: key = (srcHalf, col). rank[e] = slot within key segment.
//    The only atomic pass in the pipeline.
// ---------------------------------------------------------------------------
__global__ __launch_bounds__(256) void rank_kernel(
    const int* __restrict__ edges, int* __restrict__ cnt, int* __restrict__ rank) {
  int b = blockIdx.y;
  int e = blockIdx.x * 256 + threadIdx.x;
  int row = edges[(size_t)b * 2 * EE + e];
  int col = edges[(size_t)b * 2 * EE + EE + e];
  int key = ((row >= HALFN) ? NN : 0) + col;
  rank[(size_t)b * EE + e] = atomicAdd(&cnt[b * NK2 + key], 1);
}

// ---------------------------------------------------------------------------
// 2) exclusive scan of cnt (20000 keys) -> rowstart, one block per graph
// ---------------------------------------------------------------------------
__global__ __launch_bounds__(256) void scan_kernel(
    const int* __restrict__ cnt, int* __restrict__ rowstart) {
  int b = blockIdx.x, t = threadIdx.x;
  __shared__ int s[256];
  int running = 0;
  for (int base = 0; base < NK2; base += 2048) {
    int v[8];
    int i0 = base + t * 8;
    int tsum = 0;
#pragma unroll
    for (int j = 0; j < 8; ++j) {
      v[j] = (i0 + j < NK2) ? cnt[b * NK2 + i0 + j] : 0;
      tsum += v[j];
    }
    s[t] = tsum;
    __syncthreads();
    for (int o = 1; o < 256; o <<= 1) {
      int add = (t >= o) ? s[t - o] : 0;
      __syncthreads();
      s[t] += add;
      __syncthreads();
    }
    int ex = running + s[t] - tsum;
#pragma unroll
    for (int j = 0; j < 8; ++j) {
      if (i0 + j < NK2) rowstart[b * RS + i0 + j] = ex;
      ex += v[j];
    }
    int tot = s[255];
    __syncthreads();
    running += tot;
  }
  if (t == 0) rowstart[b * RS + NK2] = running;
}

// ---------------------------------------------------------------------------
// 3) fill CSR (no atomics): csr[pos] = {src, bits(w)}
// ---------------------------------------------------------------------------
__global__ __launch_bounds__(256) void fill_kernel(
    const int* __restrict__ edges, const float* __restrict__ attr,
    const int* __restrict__ rank, const int* __restrict__ rowstart,
    int2* __restrict__ csr) {
  int b = blockIdx.y;
  int e = blockIdx.x * 256 + threadIdx.x;
  int row = edges[(size_t)b * 2 * EE + e];
  int col = edges[(size_t)b * 2 * EE + EE + e];
  float w = attr[(size_t)b * EE + e];
  int key = ((row >= HALFN) ? NN : 0) + col;
  int pos = rowstart[b * RS + key] + rank[(size_t)b * EE + e];
  csr[(size_t)b * EE + pos] = make_int2(row, __float_as_int(w));
}

// ---------------------------------------------------------------------------
// 4) deg/dinv: sum both src-half segments of node n
// ---------------------------------------------------------------------------
__global__ __launch_bounds__(256) void deg_kernel(
    const int2* __restrict__ csr, const int* __restrict__ rowstart,
    float* __restrict__ dinv) {
  int b = blockIdx.y;
  int n = blockIdx.x * 256 + threadIdx.x;
  if (n >= NN) return;
  const int2* c = csr + (size_t)b * EE;
  float sum = 0.f;
#pragma unroll
  for (int q = 0; q < 2; ++q) {
    int key = q * NN + n;
    int s0 = rowstart[b * RS + key], s1 = rowstart[b * RS + key + 1];
    for (int i = s0; i < s1; ++i) sum += __int_as_float(c[i].y);
  }
  dinv[b * NN + n] = sum > 0.f ? rsqrtf(sum) : 0.f;
}

// ---------------------------------------------------------------------------
// 5) normalize in place: w -> dinv[col]*w*dinv[src]; wave per node, both segs
// ---------------------------------------------------------------------------
__global__ __launch_bounds__(256) void norm_kernel(
    int2* __restrict__ csr, const int* __restrict__ rowstart,
    const float* __restrict__ dinv) {
  int b = blockIdx.y;
  int n = blockIdx.x * 4 + (threadIdx.x >> 6);
  int lane = threadIdx.x & 63;
  float dc = dinv[b * NN + n];
  int2* c = csr + (size_t)b * EE;
#pragma unroll
  for (int q = 0; q < 2; ++q) {
    int key = q * NN + n;
    int s0 = rowstart[b * RS + key], s1 = rowstart[b * RS + key + 1];
    for (int i = s0 + lane; i < s1; i += 64) {
      int2 e = c[i];
      c[i].y = __float_as_int(dc * __int_as_float(e.y) * dinv[b * NN + e.x]);
    }
  }
}

// ---------------------------------------------------------------------------
// 6) register-tiled GEMM: 64 rows/block, thread = 4 rows x 8 cols.
//    xs transposed [k][row] stride 68 (conflict-free broadcast b128 reads),
//    ws [k][f(c)] stride 144, f(c)=c+((c>>5)<<2) -> 2-way (free) read banks.
// ---------------------------------------------------------------------------
__global__ __launch_bounds__(256) void gemm_kernel(
    const float* __restrict__ x, const float* __restrict__ W,
    float* __restrict__ out) {
  __shared__ float xs[32 * 68];
  __shared__ float ws[32 * 144];
  int b = blockIdx.y;
  int row0 = blockIdx.x * 64;
  int t = threadIdx.x;
  int rg = t >> 4, cg = t & 15;
  int fc = cg * 8 + ((cg >> 2) << 2);
  float acc[4][8];
#pragma unroll
  for (int r = 0; r < 4; ++r)
#pragma unroll
    for (int j = 0; j < 8; ++j) acc[r][j] = 0.f;
  const float* xb = x + (size_t)b * NN * HH;

  for (int k0 = 0; k0 < HH; k0 += 32) {
#pragma unroll
    for (int i = 0; i < 2; ++i) {
      int idx = t + i * 256;          // 0..511
      int rl = idx >> 3, kq = idx & 7;
      int row = row0 + rl;
      float4 v = make_float4(0.f, 0.f, 0.f, 0.f);
      if (row < NN) v = *(const float4*)(xb + (size_t)row * HH + k0 + kq * 4);
      xs[(kq * 4 + 0) * 68 + rl] = v.x;
      xs[(kq * 4 + 1) * 68 + rl] = v.y;
      xs[(kq * 4 + 2) * 68 + rl] = v.z;
      xs[(kq * 4 + 3) * 68 + rl] = v.w;
    }
#pragma unroll
    for (int i = 0; i < 4; ++i) {
      int idx = t + i * 256;          // 0..1023
      int kk = idx >> 5, c = (idx & 31) * 4;
      float4 v = *(const float4*)(W + (size_t)(k0 + kk) * HH + c);
      int f = c + ((c >> 5) << 2);
      *(float4*)&ws[kk * 144 + f] = v;
    }
    __syncthreads();
#pragma unroll 4
    for (int k = 0; k < 32; ++k) {
      float4 xv = *(const float4*)&xs[k * 68 + rg * 4];
      float4 w0 = *(const float4*)&ws[k * 144 + fc];
      float4 w1 = *(const float4*)&ws[k * 144 + fc + 4];
      const float* xp = (const float*)&xv;
#pragma unroll
      for (int r = 0; r < 4; ++r) {
        acc[r][0] += xp[r] * w0.x; acc[r][1] += xp[r] * w0.y;
        acc[r][2] += xp[r] * w0.z; acc[r][3] += xp[r] * w0.w;
        acc[r][4] += xp[r] * w1.x; acc[r][5] += xp[r] * w1.y;
        acc[r][6] += xp[r] * w1.z; acc[r][7] += xp[r] * w1.w;
      }
    }
    __syncthreads();
  }
#pragma unroll
  for (int r = 0; r < 4; ++r) {
    int row = row0 + rg * 4 + r;
    if (row < NN) {
      float* og = out + ((size_t)b * NN + row) * HH + cg * 8;
      *(float4*)og = make_float4(acc[r][0], acc[r][1], acc[r][2], acc[r][3]);
      *(float4*)(og + 4) = make_float4(acc[r][4], acc[r][5], acc[r][6], acc[r][7]);
    }
  }
}

// ---------------------------------------------------------------------------
// 7) aggregation, src-half split for XCD-L2 residency.
//    Group g = bid&7 -> (graph b = g>>1, src-half q = g&1): gathers ONLY from
//    xw rows [q*5000, q*5000+5000) = 2.56 MB, resident in that XCD's 4MB L2.
//    phase 0: nodes in half q,   h  = partial
//    phase 1: nodes in half 1-q, h += partial, then +bias, ReLU (single writer)
// ---------------------------------------------------------------------------
__global__ __launch_bounds__(256) void agg_kernel(
    const float* __restrict__ xw, const int2* __restrict__ csr,
    const int* __restrict__ rowstart, const float* __restrict__ bias,
    float* __restrict__ h, int phase) {
  int g = blockIdx.x & 7;
  int b = g >> 1;
  int q = g & 1;                      // src half gathered by this group
  int chunk = blockIdx.x >> 3;        // 0..1249
  int nhalf = (phase == 0) ? q : 1 - q;
  int n = nhalf * HALFN + chunk * 4 + (threadIdx.x >> 6);
  int lane = threadIdx.x & 63;
  int key = q * NN + n;
  int s0 = rowstart[b * RS + key], s1 = rowstart[b * RS + key + 1];
  const float* xwg = xw + (size_t)b * NN * HH;
  const int2* c = csr + (size_t)b * EE;
  float ax = 0.f, ay = 0.f, bx = 0.f, by = 0.f;
  int i = s0;
  for (; i + 2 <= s1; i += 2) {
    int2 e0 = c[i];
    int2 e1 = c[i + 1];
    float2 v0 = *(const float2*)(xwg + (size_t)e0.x * HH + lane * 2);
    float2 v1 = *(const float2*)(xwg + (size_t)e1.x * HH + lane * 2);
    float w0 = __int_as_float(e0.y);
    float w1 = __int_as_float(e1.y);
    ax += w0 * v0.x; ay += w0 * v0.y;
    bx += w1 * v1.x; by += w1 * v1.y;
  }
  if (i < s1) {
    int2 e0 = c[i];
    float2 v0 = *(const float2*)(xwg + (size_t)e0.x * HH + lane * 2);
    float w0 = __int_as_float(e0.y);
    ax += w0 * v0.x; ay += w0 * v0.y;
  }
  ax += bx; ay += by;
  float* hp = h + ((size_t)b * NN + n) * HH + lane * 2;
  if (phase == 0) {
    *(float2*)hp = make_float2(ax, ay);
  } else {
    float2 prev = *(const float2*)hp;
    float2 bb = *(const float2*)(bias + lane * 2);
    *(float2*)hp = make_float2(fmaxf(prev.x + ax + bb.x, 0.f),
                               fmaxf(prev.y + ay + bb.y, 0.f));
  }
}

// ---------------------------------------------------------------------------
// 8) readout
// ---------------------------------------------------------------------------
__global__ __launch_bounds__(64) void init_out_kernel(float* out, const float* __restrict__ bl) {
  if (threadIdx.x < BB) out[threadIdx.x] = bl[0];
}

__global__ __launch_bounds__(256) void final_kernel(
    const float* __restrict__ h, const float* __restrict__ Wl,
    float* __restrict__ out) {
  int b = blockIdx.y;
  int t = threadIdx.x;
  int f = t & 127;
  int rr = t >> 7;
  float p = 0.f;
  for (int n = blockIdx.x * 2 + rr; n < NN; n += gridDim.x * 2)
    p += h[((size_t)b * NN + n) * HH + f];
  __shared__ float s[256];
  s[t] = p;
  __syncthreads();
  float v = 0.f;
  if (t < 128) v = (s[t] + s[t + 128]) * Wl[f];
  __syncthreads();
  s[t] = v;
  __syncthreads();
  for (int o = 64; o > 0; o >>= 1) {
    if (t < o) s[t] += s[t + o];
    __syncthreads();
  }
  if (t == 0) atomicAdd(&out[b], s[0] * (1.0f / NN));
}

// ---------------------------------------------------------------------------
extern "C" void kernel_launch(void* const* d_in, const int* in_sizes, int n_in,
                              void* d_out, int out_size, void* d_ws, size_t ws_size,
                              hipStream_t stream) {
  const float* feat = (const float*)d_in[0];
  const int* edges = (const int*)d_in[1];
  const float* attr = (const float*)d_in[2];
  const float* W1 = (const float*)d_in[3];
  const float* b1 = (const float*)d_in[4];
  const float* W2 = (const float*)d_in[5];
  const float* b2 = (const float*)d_in[6];
  const float* W3 = (const float*)d_in[7];
  const float* b3 = (const float*)d_in[8];
  const float* Wl = (const float*)d_in[9];
  const float* bl = (const float*)d_in[10];
  float* out = (float*)d_out;

  char* ws = (char*)d_ws;
  size_t off = 0;
  auto alloc = [&](size_t bytes) {
    size_t o = off;
    off = (off + bytes + 255) & ~(size_t)255;
    return o;
  };
  int*   cnt      = (int*)  (ws + alloc((size_t)BB * NK2 * 4));        // 320 KB
  int*   rowstart = (int*)  (ws + alloc((size_t)BB * RS * 4));         // 320 KB
  int2*  csr      = (int2*) (ws + alloc((size_t)BB * EE * 8));         // 10.24 MB
  float* xw       = (float*)(ws + alloc((size_t)BB * NN * HH * 4));    // 20.48 MB
  float* h        = (float*)(ws + alloc((size_t)BB * NN * HH * 4));    // 20.48 MB
  // transient aliases (dead before gemm/agg touch xw/h):
  int*   rank = (int*)xw;     // used rank_kernel..fill_kernel
  float* dinv = (float*)h;    // used deg_kernel..norm_kernel

  (void)hipMemsetAsync(cnt, 0, (size_t)BB * NK2 * 4, stream);

  dim3 egrid(EE / 256, BB);
  rank_kernel<<<egrid, 256, 0, stream>>>(edges, cnt, rank);
  scan_kernel<<<BB, 256, 0, stream>>>(cnt, rowstart);
  fill_kernel<<<egrid, 256, 0, stream>>>(edges, attr, rank, rowstart, csr);
  deg_kernel<<<dim3((NN + 255) / 256, BB), 256, 0, stream>>>(csr, rowstart, dinv);
  norm_kernel<<<dim3(NN / 4, BB), 256, 0, stream>>>(csr, rowstart, dinv);

  dim3 ggrid((NN + 63) / 64, BB);
  int agrid = 8 * (HALFN / 4);   // 8 XCD-groups x 1250 chunks

  // layer 1
  gemm_kernel<<<ggrid, 256, 0, stream>>>(feat, W1, xw);
  agg_kernel<<<agrid, 256, 0, stream>>>(xw, csr, rowstart, b1, h, 0);
  agg_kernel<<<agrid, 256, 0, stream>>>(xw, csr, rowstart, b1, h, 1);
  // layer 2
  gemm_kernel<<<ggrid, 256, 0, stream>>>(h, W2, xw);
  agg_kernel<<<agrid, 256, 0, stream>>>(xw, csr, rowstart, b2, h, 0);
  agg_kernel<<<agrid, 256, 0, stream>>>(xw, csr, rowstart, b2, h, 1);
  // layer 3
  gemm_kernel<<<ggrid, 256, 0, stream>>>(h, W3, xw);
  agg_kernel<<<agrid, 256, 0, stream>>>(xw, csr, rowstart, b3, h, 0);
  agg_kernel<<<agrid, 256, 0, stream>>>(xw, csr, rowstart, b3, h, 1);

  init_out_kernel<<<1, 64, 0, stream>>>(out, bl);
  final_kernel<<<dim3(64, BB), 256, 0, stream>>>(h, Wl, out);
}

// Round 10
// 391.213 us; speedup vs baseline: 2.2925x; 1.1954x over previous
//
#include <hip/hip_runtime.h>

#define BB 4
#define NN 10000
#define EE 320000
#define HH 128
#define HALFN 5000
#define NK2 (2 * NN)       // CSR keys per graph: (srcHalf, col)
#define RS (2 * NN + 1)

// ---------------------------------------------------------------------------
// 1) rank pass: key = (srcHalf, col). rank[e] = slot within key segment.
//    2 edges/thread, int2-vectorized. The only atomic pass in the pipeline.
// ---------------------------------------------------------------------------
__global__ __launch_bounds__(256) void rank_kernel(
    const int* __restrict__ edges, int* __restrict__ cnt, int* __restrict__ rank) {
  int b = blockIdx.y;
  int e0 = (blockIdx.x * 256 + threadIdx.x) * 2;
  int2 rr = *(const int2*)(edges + (size_t)b * 2 * EE + e0);
  int2 cc = *(const int2*)(edges + (size_t)b * 2 * EE + EE + e0);
  int k0 = ((rr.x >= HALFN) ? NN : 0) + cc.x;
  int k1 = ((rr.y >= HALFN) ? NN : 0) + cc.y;
  int r0 = atomicAdd(&cnt[b * NK2 + k0], 1);
  int r1 = atomicAdd(&cnt[b * NK2 + k1], 1);
  *(int2*)(rank + (size_t)b * EE + e0) = make_int2(r0, r1);
}

// ---------------------------------------------------------------------------
// 2) exclusive scan of cnt (20000 keys) -> rowstart, one block per graph
// ---------------------------------------------------------------------------
__global__ __launch_bounds__(256) void scan_kernel(
    const int* __restrict__ cnt, int* __restrict__ rowstart) {
  int b = blockIdx.x, t = threadIdx.x;
  __shared__ int s[256];
  int running = 0;
  for (int base = 0; base < NK2; base += 2048) {
    int v[8];
    int i0 = base + t * 8;
    int tsum = 0;
#pragma unroll
    for (int j = 0; j < 8; ++j) {
      v[j] = (i0 + j < NK2) ? cnt[b * NK2 + i0 + j] : 0;
      tsum += v[j];
    }
    s[t] = tsum;
    __syncthreads();
    for (int o = 1; o < 256; o <<= 1) {
      int add = (t >= o) ? s[t - o] : 0;
      __syncthreads();
      s[t] += add;
      __syncthreads();
    }
    int ex = running + s[t] - tsum;
#pragma unroll
    for (int j = 0; j < 8; ++j) {
      if (i0 + j < NK2) rowstart[b * RS + i0 + j] = ex;
      ex += v[j];
    }
    int tot = s[255];
    __syncthreads();
    running += tot;
  }
  if (t == 0) rowstart[b * RS + NK2] = running;
}

// ---------------------------------------------------------------------------
// 3) fill CSR (no atomics), 2 edges/thread: csr[pos] = {src, bits(w)}
// ---------------------------------------------------------------------------
__global__ __launch_bounds__(256) void fill_kernel(
    const int* __restrict__ edges, const float* __restrict__ attr,
    const int* __restrict__ rank, const int* __restrict__ rowstart,
    int2* __restrict__ csr) {
  int b = blockIdx.y;
  int e0 = (blockIdx.x * 256 + threadIdx.x) * 2;
  int2 rr = *(const int2*)(edges + (size_t)b * 2 * EE + e0);
  int2 cc = *(const int2*)(edges + (size_t)b * 2 * EE + EE + e0);
  float2 ww = *(const float2*)(attr + (size_t)b * EE + e0);
  int2 rk = *(const int2*)(rank + (size_t)b * EE + e0);
  int k0 = ((rr.x >= HALFN) ? NN : 0) + cc.x;
  int k1 = ((rr.y >= HALFN) ? NN : 0) + cc.y;
  int p0 = rowstart[b * RS + k0] + rk.x;
  int p1 = rowstart[b * RS + k1] + rk.y;
  csr[(size_t)b * EE + p0] = make_int2(rr.x, __float_as_int(ww.x));
  csr[(size_t)b * EE + p1] = make_int2(rr.y, __float_as_int(ww.y));
}

// ---------------------------------------------------------------------------
// 4) deg/dinv: sum both src-half segments of node n
// ---------------------------------------------------------------------------
__global__ __launch_bounds__(256) void deg_kernel(
    const int2* __restrict__ csr, const int* __restrict__ rowstart,
    float* __restrict__ dinv) {
  int b = blockIdx.y;
  int n = blockIdx.x * 256 + threadIdx.x;
  if (n >= NN) return;
  const int2* c = csr + (size_t)b * EE;
  float sum = 0.f;
#pragma unroll
  for (int q = 0; q < 2; ++q) {
    int key = q * NN + n;
    int s0 = rowstart[b * RS + key], s1 = rowstart[b * RS + key + 1];
    for (int i = s0; i < s1; ++i) sum += __int_as_float(c[i].y);
  }
  dinv[b * NN + n] = sum > 0.f ? rsqrtf(sum) : 0.f;
}

// ---------------------------------------------------------------------------
// 5) normalize in place: w -> dinv[col]*w*dinv[src]; wave per node, both segs
// ---------------------------------------------------------------------------
__global__ __launch_bounds__(256) void norm_kernel(
    int2* __restrict__ csr, const int* __restrict__ rowstart,
    const float* __restrict__ dinv) {
  int b = blockIdx.y;
  int n = blockIdx.x * 4 + (threadIdx.x >> 6);
  int lane = threadIdx.x & 63;
  float dc = dinv[b * NN + n];
  int2* c = csr + (size_t)b * EE;
#pragma unroll
  for (int q = 0; q < 2; ++q) {
    int key = q * NN + n;
    int s0 = rowstart[b * RS + key], s1 = rowstart[b * RS + key + 1];
    for (int i = s0 + lane; i < s1; i += 64) {
      int2 e = c[i];
      c[i].y = __float_as_int(dc * __int_as_float(e.y) * dinv[b * NN + e.x]);
    }
  }
}

// ---------------------------------------------------------------------------
// 6) register-tiled GEMM: 64 rows/block, thread = 4 rows x 8 cols.
//    xs transposed [k][row] stride 68 (conflict-free broadcast b128 reads),
//    ws [k][f(c)] stride 144, f(c)=c+((c>>5)<<2) -> 2-way (free) read banks.
// ---------------------------------------------------------------------------
__global__ __launch_bounds__(256) void gemm_kernel(
    const float* __restrict__ x, const float* __restrict__ W,
    float* __restrict__ out) {
  __shared__ float xs[32 * 68];
  __shared__ float ws[32 * 144];
  int b = blockIdx.y;
  int row0 = blockIdx.x * 64;
  int t = threadIdx.x;
  int rg = t >> 4, cg = t & 15;
  int fc = cg * 8 + ((cg >> 2) << 2);
  float acc[4][8];
#pragma unroll
  for (int r = 0; r < 4; ++r)
#pragma unroll
    for (int j = 0; j < 8; ++j) acc[r][j] = 0.f;
  const float* xb = x + (size_t)b * NN * HH;

  for (int k0 = 0; k0 < HH; k0 += 32) {
#pragma unroll
    for (int i = 0; i < 2; ++i) {
      int idx = t + i * 256;          // 0..511
      int rl = idx >> 3, kq = idx & 7;
      int row = row0 + rl;
      float4 v = make_float4(0.f, 0.f, 0.f, 0.f);
      if (row < NN) v = *(const float4*)(xb + (size_t)row * HH + k0 + kq * 4);
      xs[(kq * 4 + 0) * 68 + rl] = v.x;
      xs[(kq * 4 + 1) * 68 + rl] = v.y;
      xs[(kq * 4 + 2) * 68 + rl] = v.z;
      xs[(kq * 4 + 3) * 68 + rl] = v.w;
    }
#pragma unroll
    for (int i = 0; i < 4; ++i) {
      int idx = t + i * 256;          // 0..1023
      int kk = idx >> 5, c = (idx & 31) * 4;
      float4 v = *(const float4*)(W + (size_t)(k0 + kk) * HH + c);
      int f = c + ((c >> 5) << 2);
      *(float4*)&ws[kk * 144 + f] = v;
    }
    __syncthreads();
#pragma unroll 4
    for (int k = 0; k < 32; ++k) {
      float4 xv = *(const float4*)&xs[k * 68 + rg * 4];
      float4 w0 = *(const float4*)&ws[k * 144 + fc];
      float4 w1 = *(const float4*)&ws[k * 144 + fc + 4];
      const float* xp = (const float*)&xv;
#pragma unroll
      for (int r = 0; r < 4; ++r) {
        acc[r][0] += xp[r] * w0.x; acc[r][1] += xp[r] * w0.y;
        acc[r][2] += xp[r] * w0.z; acc[r][3] += xp[r] * w0.w;
        acc[r][4] += xp[r] * w1.x; acc[r][5] += xp[r] * w1.y;
        acc[r][6] += xp[r] * w1.z; acc[r][7] += xp[r] * w1.w;
      }
    }
    __syncthreads();
  }
#pragma unroll
  for (int r = 0; r < 4; ++r) {
    int row = row0 + rg * 4 + r;
    if (row < NN) {
      float* og = out + ((size_t)b * NN + row) * HH + cg * 8;
      *(float4*)og = make_float4(acc[r][0], acc[r][1], acc[r][2], acc[r][3]);
      *(float4*)(og + 4) = make_float4(acc[r][4], acc[r][5], acc[r][6], acc[r][7]);
    }
  }
}

// ---------------------------------------------------------------------------
// 7) aggregation, src-half split for XCD-L2 residency.
//    Group g = bid&7 -> (graph b = g>>1, src-half q = g&1): gathers ONLY from
//    xw rows [q*5000, q*5000+5000) = 2.56 MB, resident in that XCD's 4MB L2.
//    Half-wave (32 lanes) per node, lane owns 4 features (float4) -> 2x MLP
//    vs 64-lane/node. phase 0: h = partial; phase 1: h += partial,+bias,ReLU.
// ---------------------------------------------------------------------------
__global__ __launch_bounds__(256) void agg_kernel(
    const float* __restrict__ xw, const int2* __restrict__ csr,
    const int* __restrict__ rowstart, const float* __restrict__ bias,
    float* __restrict__ h, int phase) {
  int g = blockIdx.x & 7;
  int b = g >> 1;
  int q = g & 1;                      // src half gathered by this group
  int chunk = blockIdx.x >> 3;        // 0..624
  int nhalf = (phase == 0) ? q : 1 - q;
  int half = (threadIdx.x >> 5) & 1;
  int n = nhalf * HALFN + chunk * 8 + (threadIdx.x >> 6) * 2 + half;
  int sl = threadIdx.x & 31;
  int key = q * NN + n;
  int s0 = rowstart[b * RS + key], s1 = rowstart[b * RS + key + 1];
  const float* xwg = xw + (size_t)b * NN * HH;
  const int2* c = csr + (size_t)b * EE;
  float4 a0 = make_float4(0.f, 0.f, 0.f, 0.f);
  float4 a1 = make_float4(0.f, 0.f, 0.f, 0.f);
  int i = s0;
  for (; i + 2 <= s1; i += 2) {
    int2 e0 = c[i];
    int2 e1 = c[i + 1];
    float4 v0 = *(const float4*)(xwg + (size_t)e0.x * HH + sl * 4);
    float4 v1 = *(const float4*)(xwg + (size_t)e1.x * HH + sl * 4);
    float w0 = __int_as_float(e0.y);
    float w1 = __int_as_float(e1.y);
    a0.x += w0 * v0.x; a0.y += w0 * v0.y; a0.z += w0 * v0.z; a0.w += w0 * v0.w;
    a1.x += w1 * v1.x; a1.y += w1 * v1.y; a1.z += w1 * v1.z; a1.w += w1 * v1.w;
  }
  if (i < s1) {
    int2 e0 = c[i];
    float4 v0 = *(const float4*)(xwg + (size_t)e0.x * HH + sl * 4);
    float w0 = __int_as_float(e0.y);
    a0.x += w0 * v0.x; a0.y += w0 * v0.y; a0.z += w0 * v0.z; a0.w += w0 * v0.w;
  }
  a0.x += a1.x; a0.y += a1.y; a0.z += a1.z; a0.w += a1.w;
  float* hp = h + ((size_t)b * NN + n) * HH + sl * 4;
  if (phase == 0) {
    *(float4*)hp = a0;
  } else {
    float4 prev = *(const float4*)hp;
    float4 bb = *(const float4*)(bias + sl * 4);
    *(float4*)hp = make_float4(fmaxf(prev.x + a0.x + bb.x, 0.f),
                               fmaxf(prev.y + a0.y + bb.y, 0.f),
                               fmaxf(prev.z + a0.z + bb.z, 0.f),
                               fmaxf(prev.w + a0.w + bb.w, 0.f));
  }
}

// ---------------------------------------------------------------------------
// 8) readout
// ---------------------------------------------------------------------------
__global__ __launch_bounds__(64) void init_out_kernel(float* out, const float* __restrict__ bl) {
  if (threadIdx.x < BB) out[threadIdx.x] = bl[0];
}

__global__ __launch_bounds__(256) void final_kernel(
    const float* __restrict__ h, const float* __restrict__ Wl,
    float* __restrict__ out) {
  int b = blockIdx.y;
  int t = threadIdx.x;
  int f = t & 127;
  int rr = t >> 7;
  float p = 0.f;
  for (int n = blockIdx.x * 2 + rr; n < NN; n += gridDim.x * 2)
    p += h[((size_t)b * NN + n) * HH + f];
  __shared__ float s[256];
  s[t] = p;
  __syncthreads();
  float v = 0.f;
  if (t < 128) v = (s[t] + s[t + 128]) * Wl[f];
  __syncthreads();
  s[t] = v;
  __syncthreads();
  for (int o = 64; o > 0; o >>= 1) {
    if (t < o) s[t] += s[t + o];
    __syncthreads();
  }
  if (t == 0) atomicAdd(&out[b], s[0] * (1.0f / NN));
}

// ---------------------------------------------------------------------------
extern "C" void kernel_launch(void* const* d_in, const int* in_sizes, int n_in,
                              void* d_out, int out_size, void* d_ws, size_t ws_size,
                              hipStream_t stream) {
  const float* feat = (const float*)d_in[0];
  const int* edges = (const int*)d_in[1];
  const float* attr = (const float*)d_in[2];
  const float* W1 = (const float*)d_in[3];
  const float* b1 = (const float*)d_in[4];
  const float* W2 = (const float*)d_in[5];
  const float* b2 = (const float*)d_in[6];
  const float* W3 = (const float*)d_in[7];
  const float* b3 = (const float*)d_in[8];
  const float* Wl = (const float*)d_in[9];
  const float* bl = (const float*)d_in[10];
  float* out = (float*)d_out;

  char* ws = (char*)d_ws;
  size_t off = 0;
  auto alloc = [&](size_t bytes) {
    size_t o = off;
    off = (off + bytes + 255) & ~(size_t)255;
    return o;
  };
  int*   cnt      = (int*)  (ws + alloc((size_t)BB * NK2 * 4));        // 320 KB
  int*   rowstart = (int*)  (ws + alloc((size_t)BB * RS * 4));         // 320 KB
  int2*  csr      = (int2*) (ws + alloc((size_t)BB * EE * 8));         // 10.24 MB
  float* xw       = (float*)(ws + alloc((size_t)BB * NN * HH * 4));    // 20.48 MB
  float* h        = (float*)(ws + alloc((size_t)BB * NN * HH * 4));    // 20.48 MB
  // transient aliases (dead before gemm/agg touch xw/h):
  int*   rank = (int*)xw;     // used rank_kernel..fill_kernel
  float* dinv = (float*)h;    // used deg_kernel..norm_kernel

  (void)hipMemsetAsync(cnt, 0, (size_t)BB * NK2 * 4, stream);

  dim3 egrid2(EE / 512, BB);   // 2 edges/thread
  rank_kernel<<<egrid2, 256, 0, stream>>>(edges, cnt, rank);
  scan_kernel<<<BB, 256, 0, stream>>>(cnt, rowstart);
  fill_kernel<<<egrid2, 256, 0, stream>>>(edges, attr, rank, rowstart, csr);
  deg_kernel<<<dim3((NN + 255) / 256, BB), 256, 0, stream>>>(csr, rowstart, dinv);
  norm_kernel<<<dim3(NN / 4, BB), 256, 0, stream>>>(csr, rowstart, dinv);

  dim3 ggrid((NN + 63) / 64, BB);
  int agrid = 8 * (HALFN / 8);   // 8 XCD-groups x 625 chunks (8 nodes/block)

  // layer 1
  gemm_kernel<<<ggrid, 256, 0, stream>>>(feat, W1, xw);
  agg_kernel<<<agrid, 256, 0, stream>>>(xw, csr, rowstart, b1, h, 0);
  agg_kernel<<<agrid, 256, 0, stream>>>(xw, csr, rowstart, b1, h, 1);
  // layer 2
  gemm_kernel<<<ggrid, 256, 0, stream>>>(h, W2, xw);
  agg_kernel<<<agrid, 256, 0, stream>>>(xw, csr, rowstart, b2, h, 0);
  agg_kernel<<<agrid, 256, 0, stream>>>(xw, csr, rowstart, b2, h, 1);
  // layer 3
  gemm_kernel<<<ggrid, 256, 0, stream>>>(h, W3, xw);
  agg_kernel<<<agrid, 256, 0, stream>>>(xw, csr, rowstart, b3, h, 0);
  agg_kernel<<<agrid, 256, 0, stream>>>(xw, csr, rowstart, b3, h, 1);

  init_out_kernel<<<1, 64, 0, stream>>>(out, bl);
  final_kernel<<<dim3(64, BB), 256, 0, stream>>>(h, Wl, out);
}

// Round 11
// 381.880 us; speedup vs baseline: 2.3486x; 1.0244x over previous
//
#include <hip/hip_runtime.h>

#define BB 4
#define NN 10000
#define EE 320000
#define HH 128
#define HALFN 5000
#define NK2 (2 * NN)       // CSR keys per graph: (srcHalf, col)
#define RS (2 * NN + 1)

// ---------------------------------------------------------------------------
// 1) rank pass: key = (srcHalf, col). rank[e] = slot within key segment.
//    2 edges/thread, int2-vectorized. The only atomic pass in the pipeline.
// ---------------------------------------------------------------------------
__global__ __launch_bounds__(256) void rank_kernel(
    const int* __restrict__ edges, int* __restrict__ cnt, int* __restrict__ rank) {
  int b = blockIdx.y;
  int e0 = (blockIdx.x * 256 + threadIdx.x) * 2;
  int2 rr = *(const int2*)(edges + (size_t)b * 2 * EE + e0);
  int2 cc = *(const int2*)(edges + (size_t)b * 2 * EE + EE + e0);
  int k0 = ((rr.x >= HALFN) ? NN : 0) + cc.x;
  int k1 = ((rr.y >= HALFN) ? NN : 0) + cc.y;
  int r0 = atomicAdd(&cnt[b * NK2 + k0], 1);
  int r1 = atomicAdd(&cnt[b * NK2 + k1], 1);
  *(int2*)(rank + (size_t)b * EE + e0) = make_int2(r0, r1);
}

// ---------------------------------------------------------------------------
// 2) exclusive scan of cnt (20000 keys) -> rowstart, one block per graph
// ---------------------------------------------------------------------------
__global__ __launch_bounds__(256) void scan_kernel(
    const int* __restrict__ cnt, int* __restrict__ rowstart) {
  int b = blockIdx.x, t = threadIdx.x;
  __shared__ int s[256];
  int running = 0;
  for (int base = 0; base < NK2; base += 2048) {
    int v[8];
    int i0 = base + t * 8;
    int tsum = 0;
#pragma unroll
    for (int j = 0; j < 8; ++j) {
      v[j] = (i0 + j < NK2) ? cnt[b * NK2 + i0 + j] : 0;
      tsum += v[j];
    }
    s[t] = tsum;
    __syncthreads();
    for (int o = 1; o < 256; o <<= 1) {
      int add = (t >= o) ? s[t - o] : 0;
      __syncthreads();
      s[t] += add;
      __syncthreads();
    }
    int ex = running + s[t] - tsum;
#pragma unroll
    for (int j = 0; j < 8; ++j) {
      if (i0 + j < NK2) rowstart[b * RS + i0 + j] = ex;
      ex += v[j];
    }
    int tot = s[255];
    __syncthreads();
    running += tot;
  }
  if (t == 0) rowstart[b * RS + NK2] = running;
}

// ---------------------------------------------------------------------------
// 3) fill CSR (no atomics), 2 edges/thread: csr[pos] = {src, bits(raw w)}
// ---------------------------------------------------------------------------
__global__ __launch_bounds__(256) void fill_kernel(
    const int* __restrict__ edges, const float* __restrict__ attr,
    const int* __restrict__ rank, const int* __restrict__ rowstart,
    int2* __restrict__ csr) {
  int b = blockIdx.y;
  int e0 = (blockIdx.x * 256 + threadIdx.x) * 2;
  int2 rr = *(const int2*)(edges + (size_t)b * 2 * EE + e0);
  int2 cc = *(const int2*)(edges + (size_t)b * 2 * EE + EE + e0);
  float2 ww = *(const float2*)(attr + (size_t)b * EE + e0);
  int2 rk = *(const int2*)(rank + (size_t)b * EE + e0);
  int k0 = ((rr.x >= HALFN) ? NN : 0) + cc.x;
  int k1 = ((rr.y >= HALFN) ? NN : 0) + cc.y;
  int p0 = rowstart[b * RS + k0] + rk.x;
  int p1 = rowstart[b * RS + k1] + rk.y;
  csr[(size_t)b * EE + p0] = make_int2(rr.x, __float_as_int(ww.x));
  csr[(size_t)b * EE + p1] = make_int2(rr.y, __float_as_int(ww.y));
}

// ---------------------------------------------------------------------------
// 4) deg/dinv: sum both src-half segments of node n (raw w), dinv = rsqrt
// ---------------------------------------------------------------------------
__global__ __launch_bounds__(256) void deg_kernel(
    const int2* __restrict__ csr, const int* __restrict__ rowstart,
    float* __restrict__ dinv) {
  int b = blockIdx.y;
  int n = blockIdx.x * 256 + threadIdx.x;
  if (n >= NN) return;
  const int2* c = csr + (size_t)b * EE;
  float sum = 0.f;
#pragma unroll
  for (int q = 0; q < 2; ++q) {
    int key = q * NN + n;
    int s0 = rowstart[b * RS + key], s1 = rowstart[b * RS + key + 1];
    for (int i = s0; i < s1; ++i) sum += __int_as_float(c[i].y);
  }
  dinv[b * NN + n] = sum > 0.f ? rsqrtf(sum) : 0.f;
}

// ---------------------------------------------------------------------------
// 5) register-tiled GEMM: 64 rows/block, thread = 4 rows x 8 cols.
//    xs transposed [k][row] stride 68 (conflict-free broadcast b128 reads),
//    ws [k][f(c)] stride 144, f(c)=c+((c>>5)<<2) -> 2-way (free) read banks.
// ---------------------------------------------------------------------------
__global__ __launch_bounds__(256) void gemm_kernel(
    const float* __restrict__ x, const float* __restrict__ W,
    float* __restrict__ out) {
  __shared__ float xs[32 * 68];
  __shared__ float ws[32 * 144];
  int b = blockIdx.y;
  int row0 = blockIdx.x * 64;
  int t = threadIdx.x;
  int rg = t >> 4, cg = t & 15;
  int fc = cg * 8 + ((cg >> 2) << 2);
  float acc[4][8];
#pragma unroll
  for (int r = 0; r < 4; ++r)
#pragma unroll
    for (int j = 0; j < 8; ++j) acc[r][j] = 0.f;
  const float* xb = x + (size_t)b * NN * HH;

  for (int k0 = 0; k0 < HH; k0 += 32) {
#pragma unroll
    for (int i = 0; i < 2; ++i) {
      int idx = t + i * 256;          // 0..511
      int rl = idx >> 3, kq = idx & 7;
      int row = row0 + rl;
      float4 v = make_float4(0.f, 0.f, 0.f, 0.f);
      if (row < NN) v = *(const float4*)(xb + (size_t)row * HH + k0 + kq * 4);
      xs[(kq * 4 + 0) * 68 + rl] = v.x;
      xs[(kq * 4 + 1) * 68 + rl] = v.y;
      xs[(kq * 4 + 2) * 68 + rl] = v.z;
      xs[(kq * 4 + 3) * 68 + rl] = v.w;
    }
#pragma unroll
    for (int i = 0; i < 4; ++i) {
      int idx = t + i * 256;          // 0..1023
      int kk = idx >> 5, c = (idx & 31) * 4;
      float4 v = *(const float4*)(W + (size_t)(k0 + kk) * HH + c);
      int f = c + ((c >> 5) << 2);
      *(float4*)&ws[kk * 144 + f] = v;
    }
    __syncthreads();
#pragma unroll 4
    for (int k = 0; k < 32; ++k) {
      float4 xv = *(const float4*)&xs[k * 68 + rg * 4];
      float4 w0 = *(const float4*)&ws[k * 144 + fc];
      float4 w1 = *(const float4*)&ws[k * 144 + fc + 4];
      const float* xp = (const float*)&xv;
#pragma unroll
      for (int r = 0; r < 4; ++r) {
        acc[r][0] += xp[r] * w0.x; acc[r][1] += xp[r] * w0.y;
        acc[r][2] += xp[r] * w0.z; acc[r][3] += xp[r] * w0.w;
        acc[r][4] += xp[r] * w1.x; acc[r][5] += xp[r] * w1.y;
        acc[r][6] += xp[r] * w1.z; acc[r][7] += xp[r] * w1.w;
      }
    }
    __syncthreads();
  }
#pragma unroll
  for (int r = 0; r < 4; ++r) {
    int row = row0 + rg * 4 + r;
    if (row < NN) {
      float* og = out + ((size_t)b * NN + row) * HH + cg * 8;
      *(float4*)og = make_float4(acc[r][0], acc[r][1], acc[r][2], acc[r][3]);
      *(float4*)(og + 4) = make_float4(acc[r][4], acc[r][5], acc[r][6], acc[r][7]);
    }
  }
}

// ---------------------------------------------------------------------------
// 6) aggregation, src-half split for XCD-L2 residency, norm folded in:
//    per edge w_e * dinv[src] (broadcast 4B load), dinv[dst] applied once in
//    phase 1. Half-wave per node, lane owns float4, 4-edge unroll for MLP.
//    phase 0: h = raw partial; phase 1: h = relu((prev+partial)*dinv[n]+bias)
// ---------------------------------------------------------------------------
__global__ __launch_bounds__(256) void agg_kernel(
    const float* __restrict__ xw, const int2* __restrict__ csr,
    const int* __restrict__ rowstart, const float* __restrict__ dinv,
    const float* __restrict__ bias, float* __restrict__ h, int phase) {
  int g = blockIdx.x & 7;
  int b = g >> 1;
  int q = g & 1;                      // src half gathered by this group
  int chunk = blockIdx.x >> 3;        // 0..624
  int nhalf = (phase == 0) ? q : 1 - q;
  int half = (threadIdx.x >> 5) & 1;
  int n = nhalf * HALFN + chunk * 8 + (threadIdx.x >> 6) * 2 + half;
  int sl = threadIdx.x & 31;
  int key = q * NN + n;
  int s0 = rowstart[b * RS + key], s1 = rowstart[b * RS + key + 1];
  const float* xwg = xw + (size_t)b * NN * HH;
  const float* dv = dinv + b * NN;
  const int2* c = csr + (size_t)b * EE;
  float4 a0 = make_float4(0.f, 0.f, 0.f, 0.f);
  float4 a1 = make_float4(0.f, 0.f, 0.f, 0.f);
  float4 a2 = make_float4(0.f, 0.f, 0.f, 0.f);
  float4 a3 = make_float4(0.f, 0.f, 0.f, 0.f);
  int i = s0;
  for (; i + 4 <= s1; i += 4) {
    int2 e0 = c[i];
    int2 e1 = c[i + 1];
    int2 e2 = c[i + 2];
    int2 e3 = c[i + 3];
    float w0 = __int_as_float(e0.y) * dv[e0.x];
    float w1 = __int_as_float(e1.y) * dv[e1.x];
    float w2 = __int_as_float(e2.y) * dv[e2.x];
    float w3 = __int_as_float(e3.y) * dv[e3.x];
    float4 v0 = *(const float4*)(xwg + (size_t)e0.x * HH + sl * 4);
    float4 v1 = *(const float4*)(xwg + (size_t)e1.x * HH + sl * 4);
    float4 v2 = *(const float4*)(xwg + (size_t)e2.x * HH + sl * 4);
    float4 v3 = *(const float4*)(xwg + (size_t)e3.x * HH + sl * 4);
    a0.x += w0 * v0.x; a0.y += w0 * v0.y; a0.z += w0 * v0.z; a0.w += w0 * v0.w;
    a1.x += w1 * v1.x; a1.y += w1 * v1.y; a1.z += w1 * v1.z; a1.w += w1 * v1.w;
    a2.x += w2 * v2.x; a2.y += w2 * v2.y; a2.z += w2 * v2.z; a2.w += w2 * v2.w;
    a3.x += w3 * v3.x; a3.y += w3 * v3.y; a3.z += w3 * v3.z; a3.w += w3 * v3.w;
  }
  for (; i < s1; ++i) {
    int2 e0 = c[i];
    float w0 = __int_as_float(e0.y) * dv[e0.x];
    float4 v0 = *(const float4*)(xwg + (size_t)e0.x * HH + sl * 4);
    a0.x += w0 * v0.x; a0.y += w0 * v0.y; a0.z += w0 * v0.z; a0.w += w0 * v0.w;
  }
  a0.x += a1.x + a2.x + a3.x;
  a0.y += a1.y + a2.y + a3.y;
  a0.z += a1.z + a2.z + a3.z;
  a0.w += a1.w + a2.w + a3.w;
  float* hp = h + ((size_t)b * NN + n) * HH + sl * 4;
  if (phase == 0) {
    *(float4*)hp = a0;
  } else {
    float dn = dv[n];
    float4 prev = *(const float4*)hp;
    float4 bb = *(const float4*)(bias + sl * 4);
    *(float4*)hp = make_float4(fmaxf((prev.x + a0.x) * dn + bb.x, 0.f),
                               fmaxf((prev.y + a0.y) * dn + bb.y, 0.f),
                               fmaxf((prev.z + a0.z) * dn + bb.z, 0.f),
                               fmaxf((prev.w + a0.w) * dn + bb.w, 0.f));
  }
}

// ---------------------------------------------------------------------------
// 7) readout
// ---------------------------------------------------------------------------
__global__ __launch_bounds__(64) void init_out_kernel(float* out, const float* __restrict__ bl) {
  if (threadIdx.x < BB) out[threadIdx.x] = bl[0];
}

__global__ __launch_bounds__(256) void final_kernel(
    const float* __restrict__ h, const float* __restrict__ Wl,
    float* __restrict__ out) {
  int b = blockIdx.y;
  int t = threadIdx.x;
  int f = t & 127;
  int rr = t >> 7;
  float p = 0.f;
  for (int n = blockIdx.x * 2 + rr; n < NN; n += gridDim.x * 2)
    p += h[((size_t)b * NN + n) * HH + f];
  __shared__ float s[256];
  s[t] = p;
  __syncthreads();
  float v = 0.f;
  if (t < 128) v = (s[t] + s[t + 128]) * Wl[f];
  __syncthreads();
  s[t] = v;
  __syncthreads();
  for (int o = 64; o > 0; o >>= 1) {
    if (t < o) s[t] += s[t + o];
    __syncthreads();
  }
  if (t == 0) atomicAdd(&out[b], s[0] * (1.0f / NN));
}

// ---------------------------------------------------------------------------
extern "C" void kernel_launch(void* const* d_in, const int* in_sizes, int n_in,
                              void* d_out, int out_size, void* d_ws, size_t ws_size,
                              hipStream_t stream) {
  const float* feat = (const float*)d_in[0];
  const int* edges = (const int*)d_in[1];
  const float* attr = (const float*)d_in[2];
  const float* W1 = (const float*)d_in[3];
  const float* b1 = (const float*)d_in[4];
  const float* W2 = (const float*)d_in[5];
  const float* b2 = (const float*)d_in[6];
  const float* W3 = (const float*)d_in[7];
  const float* b3 = (const float*)d_in[8];
  const float* Wl = (const float*)d_in[9];
  const float* bl = (const float*)d_in[10];
  float* out = (float*)d_out;

  char* ws = (char*)d_ws;
  size_t off = 0;
  auto alloc = [&](size_t bytes) {
    size_t o = off;
    off = (off + bytes + 255) & ~(size_t)255;
    return o;
  };
  int*   cnt      = (int*)  (ws + alloc((size_t)BB * NK2 * 4));        // 320 KB
  int*   rowstart = (int*)  (ws + alloc((size_t)BB * RS * 4));         // 320 KB
  int2*  csr      = (int2*) (ws + alloc((size_t)BB * EE * 8));         // 10.24 MB
  float* xw       = (float*)(ws + alloc((size_t)BB * NN * HH * 4));    // 20.48 MB
  float* h        = (float*)(ws + alloc((size_t)BB * NN * HH * 4));    // 20.48 MB
  // transient aliases:
  int*   rank = (int*)xw;       // live rank_kernel..fill_kernel (xw dead then)
  float* dinv = (float*)cnt;    // live deg_kernel..end (cnt dead after scan)

  (void)hipMemsetAsync(cnt, 0, (size_t)BB * NK2 * 4, stream);

  dim3 egrid2(EE / 512, BB);   // 2 edges/thread
  rank_kernel<<<egrid2, 256, 0, stream>>>(edges, cnt, rank);
  scan_kernel<<<BB, 256, 0, stream>>>(cnt, rowstart);
  fill_kernel<<<egrid2, 256, 0, stream>>>(edges, attr, rank, rowstart, csr);
  deg_kernel<<<dim3((NN + 255) / 256, BB), 256, 0, stream>>>(csr, rowstart, dinv);

  dim3 ggrid((NN + 63) / 64, BB);
  int agrid = 8 * (HALFN / 8);   // 8 XCD-groups x 625 chunks (8 nodes/block)

  // layer 1
  gemm_kernel<<<ggrid, 256, 0, stream>>>(feat, W1, xw);
  agg_kernel<<<agrid, 256, 0, stream>>>(xw, csr, rowstart, dinv, b1, h, 0);
  agg_kernel<<<agrid, 256, 0, stream>>>(xw, csr, rowstart, dinv, b1, h, 1);
  // layer 2
  gemm_kernel<<<ggrid, 256, 0, stream>>>(h, W2, xw);
  agg_kernel<<<agrid, 256, 0, stream>>>(xw, csr, rowstart, dinv, b2, h, 0);
  agg_kernel<<<agrid, 256, 0, stream>>>(xw, csr, rowstart, dinv, b2, h, 1);
  // layer 3
  gemm_kernel<<<ggrid, 256, 0, stream>>>(h, W3, xw);
  agg_kernel<<<agrid, 256, 0, stream>>>(xw, csr, rowstart, dinv, b3, h, 0);
  agg_kernel<<<agrid, 256, 0, stream>>>(xw, csr, rowstart, dinv, b3, h, 1);

  init_out_kernel<<<1, 64, 0, stream>>>(out, bl);
  final_kernel<<<dim3(64, BB), 256, 0, stream>>>(h, Wl, out);
}

// Round 12
// 373.329 us; speedup vs baseline: 2.4024x; 1.0229x over previous
//
#include <hip/hip_runtime.h>

#define BB 4
#define NN 10000
#define EE 320000
#define HH 128
#define HALFN 5000
#define NK2 (2 * NN)       // CSR keys per graph: (srcHalf, col)
#define RS (2 * NN + 1)
#define NHB 64             // histogram blocks per graph
#define EPB (EE / NHB)     // 5000 edges per histogram block

// ---------------------------------------------------------------------------
// 1) hist: per-block LDS histogram over keys (two half-passes), emits
//    per-edge local rank (ushort) and per-block histogram hb[blk][key].
//    NO global atomics anywhere in the pipeline now.
// ---------------------------------------------------------------------------
__global__ __launch_bounds__(256) void hist_kernel(
    const int* __restrict__ edges, int* __restrict__ hb,
    unsigned short* __restrict__ lrank) {
  __shared__ int lh[NN];   // 40 KB: one key-half at a time
  int b = blockIdx.y;
  int blk = blockIdx.x;
  int t = threadIdx.x;
  const int* rows = edges + (size_t)b * 2 * EE;
  const int* cols = rows + EE;
#pragma unroll
  for (int half = 0; half < 2; ++half) {
    for (int i = t; i < NN; i += 256) lh[i] = 0;
    __syncthreads();
    for (int i = t; i < EPB; i += 256) {
      int e = blk * EPB + i;
      int row = rows[e];
      int col = cols[e];
      if ((row >= HALFN) == (half != 0)) {
        int lr = atomicAdd(&lh[col], 1);
        lrank[(size_t)b * EE + e] = (unsigned short)lr;
      }
    }
    __syncthreads();
    int* hbrow = hb + ((size_t)(b * NHB + blk)) * NK2 + half * NN;
    for (int i = t; i < NN; i += 256) hbrow[i] = lh[i];
    __syncthreads();
  }
}

// ---------------------------------------------------------------------------
// 2) colscan: per key, exclusive prefix over the 64 block histograms
//    (in place) -> hb[blk][key] = #key-edges in blocks < blk; cnt[key]=total
// ---------------------------------------------------------------------------
__global__ __launch_bounds__(256) void colscan_kernel(
    int* __restrict__ hb, int* __restrict__ cnt) {
  int b = blockIdx.y;
  int k = blockIdx.x * 256 + threadIdx.x;
  if (k >= NK2) return;
  int acc = 0;
  for (int j = 0; j < NHB; ++j) {
    size_t idx = ((size_t)(b * NHB + j)) * NK2 + k;
    int v = hb[idx];
    hb[idx] = acc;
    acc += v;
  }
  cnt[b * NK2 + k] = acc;
}

// ---------------------------------------------------------------------------
// 3) exclusive scan of cnt (20000 keys) -> rowstart, one block per graph
// ---------------------------------------------------------------------------
__global__ __launch_bounds__(256) void scan_kernel(
    const int* __restrict__ cnt, int* __restrict__ rowstart) {
  int b = blockIdx.x, t = threadIdx.x;
  __shared__ int s[256];
  int running = 0;
  for (int base = 0; base < NK2; base += 2048) {
    int v[8];
    int i0 = base + t * 8;
    int tsum = 0;
#pragma unroll
    for (int j = 0; j < 8; ++j) {
      v[j] = (i0 + j < NK2) ? cnt[b * NK2 + i0 + j] : 0;
      tsum += v[j];
    }
    s[t] = tsum;
    __syncthreads();
    for (int o = 1; o < 256; o <<= 1) {
      int add = (t >= o) ? s[t - o] : 0;
      __syncthreads();
      s[t] += add;
      __syncthreads();
    }
    int ex = running + s[t] - tsum;
#pragma unroll
    for (int j = 0; j < 8; ++j) {
      if (i0 + j < NK2) rowstart[b * RS + i0 + j] = ex;
      ex += v[j];
    }
    int tot = s[255];
    __syncthreads();
    running += tot;
  }
  if (t == 0) rowstart[b * RS + NK2] = running;
}

// ---------------------------------------------------------------------------
// 4) fill CSR (no atomics), 2 edges/thread:
//    pos = rowstart[key] + hb[blk][key] + lrank[e]; csr[pos]={src, bits(w)}
// ---------------------------------------------------------------------------
__global__ __launch_bounds__(256) void fill_kernel(
    const int* __restrict__ edges, const float* __restrict__ attr,
    const unsigned short* __restrict__ lrank, const int* __restrict__ hb,
    const int* __restrict__ rowstart, int2* __restrict__ csr) {
  int b = blockIdx.y;
  int e0 = (blockIdx.x * 256 + threadIdx.x) * 2;
  int blk = e0 / EPB;   // both e0, e0+1 in same hist block (EPB even)
  int2 rr = *(const int2*)(edges + (size_t)b * 2 * EE + e0);
  int2 cc = *(const int2*)(edges + (size_t)b * 2 * EE + EE + e0);
  float2 ww = *(const float2*)(attr + (size_t)b * EE + e0);
  unsigned int lr2 = *(const unsigned int*)(lrank + (size_t)b * EE + e0);
  int k0 = ((rr.x >= HALFN) ? NN : 0) + cc.x;
  int k1 = ((rr.y >= HALFN) ? NN : 0) + cc.y;
  const int* hbrow = hb + ((size_t)(b * NHB + blk)) * NK2;
  int p0 = rowstart[b * RS + k0] + hbrow[k0] + (int)(lr2 & 0xffffu);
  int p1 = rowstart[b * RS + k1] + hbrow[k1] + (int)(lr2 >> 16);
  csr[(size_t)b * EE + p0] = make_int2(rr.x, __float_as_int(ww.x));
  csr[(size_t)b * EE + p1] = make_int2(rr.y, __float_as_int(ww.y));
}

// ---------------------------------------------------------------------------
// 5) deg/dinv: sum both src-half segments of node n (raw w), dinv = rsqrt
// ---------------------------------------------------------------------------
__global__ __launch_bounds__(256) void deg_kernel(
    const int2* __restrict__ csr, const int* __restrict__ rowstart,
    float* __restrict__ dinv) {
  int b = blockIdx.y;
  int n = blockIdx.x * 256 + threadIdx.x;
  if (n >= NN) return;
  const int2* c = csr + (size_t)b * EE;
  float sum = 0.f;
#pragma unroll
  for (int q = 0; q < 2; ++q) {
    int key = q * NN + n;
    int s0 = rowstart[b * RS + key], s1 = rowstart[b * RS + key + 1];
    for (int i = s0; i < s1; ++i) sum += __int_as_float(c[i].y);
  }
  dinv[b * NN + n] = sum > 0.f ? rsqrtf(sum) : 0.f;
}

// ---------------------------------------------------------------------------
// 6) register-tiled GEMM: 64 rows/block, thread = 4 rows x 8 cols.
// ---------------------------------------------------------------------------
__global__ __launch_bounds__(256) void gemm_kernel(
    const float* __restrict__ x, const float* __restrict__ W,
    float* __restrict__ out) {
  __shared__ float xs[32 * 68];
  __shared__ float ws[32 * 144];
  int b = blockIdx.y;
  int row0 = blockIdx.x * 64;
  int t = threadIdx.x;
  int rg = t >> 4, cg = t & 15;
  int fc = cg * 8 + ((cg >> 2) << 2);
  float acc[4][8];
#pragma unroll
  for (int r = 0; r < 4; ++r)
#pragma unroll
    for (int j = 0; j < 8; ++j) acc[r][j] = 0.f;
  const float* xb = x + (size_t)b * NN * HH;

  for (int k0 = 0; k0 < HH; k0 += 32) {
#pragma unroll
    for (int i = 0; i < 2; ++i) {
      int idx = t + i * 256;
      int rl = idx >> 3, kq = idx & 7;
      int row = row0 + rl;
      float4 v = make_float4(0.f, 0.f, 0.f, 0.f);
      if (row < NN) v = *(const float4*)(xb + (size_t)row * HH + k0 + kq * 4);
      xs[(kq * 4 + 0) * 68 + rl] = v.x;
      xs[(kq * 4 + 1) * 68 + rl] = v.y;
      xs[(kq * 4 + 2) * 68 + rl] = v.z;
      xs[(kq * 4 + 3) * 68 + rl] = v.w;
    }
#pragma unroll
    for (int i = 0; i < 4; ++i) {
      int idx = t + i * 256;
      int kk = idx >> 5, c = (idx & 31) * 4;
      float4 v = *(const float4*)(W + (size_t)(k0 + kk) * HH + c);
      int f = c + ((c >> 5) << 2);
      *(float4*)&ws[kk * 144 + f] = v;
    }
    __syncthreads();
#pragma unroll 4
    for (int k = 0; k < 32; ++k) {
      float4 xv = *(const float4*)&xs[k * 68 + rg * 4];
      float4 w0 = *(const float4*)&ws[k * 144 + fc];
      float4 w1 = *(const float4*)&ws[k * 144 + fc + 4];
      const float* xp = (const float*)&xv;
#pragma unroll
      for (int r = 0; r < 4; ++r) {
        acc[r][0] += xp[r] * w0.x; acc[r][1] += xp[r] * w0.y;
        acc[r][2] += xp[r] * w0.z; acc[r][3] += xp[r] * w0.w;
        acc[r][4] += xp[r] * w1.x; acc[r][5] += xp[r] * w1.y;
        acc[r][6] += xp[r] * w1.z; acc[r][7] += xp[r] * w1.w;
      }
    }
    __syncthreads();
  }
#pragma unroll
  for (int r = 0; r < 4; ++r) {
    int row = row0 + rg * 4 + r;
    if (row < NN) {
      float* og = out + ((size_t)b * NN + row) * HH + cg * 8;
      *(float4*)og = make_float4(acc[r][0], acc[r][1], acc[r][2], acc[r][3]);
      *(float4*)(og + 4) = make_float4(acc[r][4], acc[r][5], acc[r][6], acc[r][7]);
    }
  }
}

// ---------------------------------------------------------------------------
// 7) aggregation, src-half split for XCD-L2 residency, norm folded in.
// ---------------------------------------------------------------------------
__global__ __launch_bounds__(256) void agg_kernel(
    const float* __restrict__ xw, const int2* __restrict__ csr,
    const int* __restrict__ rowstart, const float* __restrict__ dinv,
    const float* __restrict__ bias, float* __restrict__ h, int phase) {
  int g = blockIdx.x & 7;
  int b = g >> 1;
  int q = g & 1;
  int chunk = blockIdx.x >> 3;
  int nhalf = (phase == 0) ? q : 1 - q;
  int half = (threadIdx.x >> 5) & 1;
  int n = nhalf * HALFN + chunk * 8 + (threadIdx.x >> 6) * 2 + half;
  int sl = threadIdx.x & 31;
  int key = q * NN + n;
  int s0 = rowstart[b * RS + key], s1 = rowstart[b * RS + key + 1];
  const float* xwg = xw + (size_t)b * NN * HH;
  const float* dv = dinv + b * NN;
  const int2* c = csr + (size_t)b * EE;
  float4 a0 = make_float4(0.f, 0.f, 0.f, 0.f);
  float4 a1 = make_float4(0.f, 0.f, 0.f, 0.f);
  float4 a2 = make_float4(0.f, 0.f, 0.f, 0.f);
  float4 a3 = make_float4(0.f, 0.f, 0.f, 0.f);
  int i = s0;
  for (; i + 4 <= s1; i += 4) {
    int2 e0 = c[i];
    int2 e1 = c[i + 1];
    int2 e2 = c[i + 2];
    int2 e3 = c[i + 3];
    float w0 = __int_as_float(e0.y) * dv[e0.x];
    float w1 = __int_as_float(e1.y) * dv[e1.x];
    float w2 = __int_as_float(e2.y) * dv[e2.x];
    float w3 = __int_as_float(e3.y) * dv[e3.x];
    float4 v0 = *(const float4*)(xwg + (size_t)e0.x * HH + sl * 4);
    float4 v1 = *(const float4*)(xwg + (size_t)e1.x * HH + sl * 4);
    float4 v2 = *(const float4*)(xwg + (size_t)e2.x * HH + sl * 4);
    float4 v3 = *(const float4*)(xwg + (size_t)e3.x * HH + sl * 4);
    a0.x += w0 * v0.x; a0.y += w0 * v0.y; a0.z += w0 * v0.z; a0.w += w0 * v0.w;
    a1.x += w1 * v1.x; a1.y += w1 * v1.y; a1.z += w1 * v1.z; a1.w += w1 * v1.w;
    a2.x += w2 * v2.x; a2.y += w2 * v2.y; a2.z += w2 * v2.z; a2.w += w2 * v2.w;
    a3.x += w3 * v3.x; a3.y += w3 * v3.y; a3.z += w3 * v3.z; a3.w += w3 * v3.w;
  }
  for (; i < s1; ++i) {
    int2 e0 = c[i];
    float w0 = __int_as_float(e0.y) * dv[e0.x];
    float4 v0 = *(const float4*)(xwg + (size_t)e0.x * HH + sl * 4);
    a0.x += w0 * v0.x; a0.y += w0 * v0.y; a0.z += w0 * v0.z; a0.w += w0 * v0.w;
  }
  a0.x += a1.x + a2.x + a3.x;
  a0.y += a1.y + a2.y + a3.y;
  a0.z += a1.z + a2.z + a3.z;
  a0.w += a1.w + a2.w + a3.w;
  float* hp = h + ((size_t)b * NN + n) * HH + sl * 4;
  if (phase == 0) {
    *(float4*)hp = a0;
  } else {
    float dn = dv[n];
    float4 prev = *(const float4*)hp;
    float4 bb = *(const float4*)(bias + sl * 4);
    *(float4*)hp = make_float4(fmaxf((prev.x + a0.x) * dn + bb.x, 0.f),
                               fmaxf((prev.y + a0.y) * dn + bb.y, 0.f),
                               fmaxf((prev.z + a0.z) * dn + bb.z, 0.f),
                               fmaxf((prev.w + a0.w) * dn + bb.w, 0.f));
  }
}

// ---------------------------------------------------------------------------
// 8) readout
// ---------------------------------------------------------------------------
__global__ __launch_bounds__(64) void init_out_kernel(float* out, const float* __restrict__ bl) {
  if (threadIdx.x < BB) out[threadIdx.x] = bl[0];
}

__global__ __launch_bounds__(256) void final_kernel(
    const float* __restrict__ h, const float* __restrict__ Wl,
    float* __restrict__ out) {
  int b = blockIdx.y;
  int t = threadIdx.x;
  int f = t & 127;
  int rr = t >> 7;
  float p = 0.f;
  for (int n = blockIdx.x * 2 + rr; n < NN; n += gridDim.x * 2)
    p += h[((size_t)b * NN + n) * HH + f];
  __shared__ float s[256];
  s[t] = p;
  __syncthreads();
  float v = 0.f;
  if (t < 128) v = (s[t] + s[t + 128]) * Wl[f];
  __syncthreads();
  s[t] = v;
  __syncthreads();
  for (int o = 64; o > 0; o >>= 1) {
    if (t < o) s[t] += s[t + o];
    __syncthreads();
  }
  if (t == 0) atomicAdd(&out[b], s[0] * (1.0f / NN));
}

// ---------------------------------------------------------------------------
extern "C" void kernel_launch(void* const* d_in, const int* in_sizes, int n_in,
                              void* d_out, int out_size, void* d_ws, size_t ws_size,
                              hipStream_t stream) {
  const float* feat = (const float*)d_in[0];
  const int* edges = (const int*)d_in[1];
  const float* attr = (const float*)d_in[2];
  const float* W1 = (const float*)d_in[3];
  const float* b1 = (const float*)d_in[4];
  const float* W2 = (const float*)d_in[5];
  const float* b2 = (const float*)d_in[6];
  const float* W3 = (const float*)d_in[7];
  const float* b3 = (const float*)d_in[8];
  const float* Wl = (const float*)d_in[9];
  const float* bl = (const float*)d_in[10];
  float* out = (float*)d_out;

  char* ws = (char*)d_ws;
  size_t off = 0;
  auto alloc = [&](size_t bytes) {
    size_t o = off;
    off = (off + bytes + 255) & ~(size_t)255;
    return o;
  };
  int*   cnt      = (int*)  (ws + alloc((size_t)BB * NK2 * 4));        // 320 KB
  int*   rowstart = (int*)  (ws + alloc((size_t)BB * RS * 4));         // 320 KB
  int2*  csr      = (int2*) (ws + alloc((size_t)BB * EE * 8));         // 10.24 MB
  float* xw       = (float*)(ws + alloc((size_t)BB * NN * HH * 4));    // 20.48 MB
  float* h        = (float*)(ws + alloc((size_t)BB * NN * HH * 4));    // 20.48 MB
  // transient aliases (dead before gemm/agg touch xw/h):
  unsigned short* lrank = (unsigned short*)xw;  // 2.56 MB, live hist..fill
  int*   hb   = (int*)h;       // BB*NHB*NK2*4 = 20.48 MB, live hist..fill
  float* dinv = (float*)cnt;   // live deg..end (cnt dead after scan)

  dim3 hgrid(NHB, BB);
  hist_kernel<<<hgrid, 256, 0, stream>>>(edges, hb, lrank);
  colscan_kernel<<<dim3((NK2 + 255) / 256, BB), 256, 0, stream>>>(hb, cnt);
  scan_kernel<<<BB, 256, 0, stream>>>(cnt, rowstart);
  dim3 egrid2(EE / 512, BB);   // 2 edges/thread
  fill_kernel<<<egrid2, 256, 0, stream>>>(edges, attr, lrank, hb, rowstart, csr);
  deg_kernel<<<dim3((NN + 255) / 256, BB), 256, 0, stream>>>(csr, rowstart, dinv);

  dim3 ggrid((NN + 63) / 64, BB);
  int agrid = 8 * (HALFN / 8);   // 8 XCD-groups x 625 chunks (8 nodes/block)

  // layer 1
  gemm_kernel<<<ggrid, 256, 0, stream>>>(feat, W1, xw);
  agg_kernel<<<agrid, 256, 0, stream>>>(xw, csr, rowstart, dinv, b1, h, 0);
  agg_kernel<<<agrid, 256, 0, stream>>>(xw, csr, rowstart, dinv, b1, h, 1);
  // layer 2
  gemm_kernel<<<ggrid, 256, 0, stream>>>(h, W2, xw);
  agg_kernel<<<agrid, 256, 0, stream>>>(xw, csr, rowstart, dinv, b2, h, 0);
  agg_kernel<<<agrid, 256, 0, stream>>>(xw, csr, rowstart, dinv, b2, h, 1);
  // layer 3
  gemm_kernel<<<ggrid, 256, 0, stream>>>(h, W3, xw);
  agg_kernel<<<agrid, 256, 0, stream>>>(xw, csr, rowstart, dinv, b3, h, 0);
  agg_kernel<<<agrid, 256, 0, stream>>>(xw, csr, rowstart, dinv, b3, h, 1);

  init_out_kernel<<<1, 64, 0, stream>>>(out, bl);
  final_kernel<<<dim3(64, BB), 256, 0, stream>>>(h, Wl, out);
}

// Round 13
// 346.971 us; speedup vs baseline: 2.5849x; 1.0760x over previous
//
#include <hip/hip_runtime.h>

#define BB 4
#define NN 10000
#define EE 320000
#define HH 128
#define HALFN 5000
#define NK2 (2 * NN)       // CSR keys per graph: (srcHalf, col)
#define RS (2 * NN + 1)
#define NHB 64             // histogram blocks per graph
#define EPB (EE / NHB)     // 5000 edges per histogram block

// ---------------------------------------------------------------------------
// 1) hist: per-block LDS histogram over keys (two half-passes), emits
//    per-edge local rank (ushort) and per-block histogram hb[blk][key].
//    No global atomics anywhere in the pipeline.
// ---------------------------------------------------------------------------
__global__ __launch_bounds__(256) void hist_kernel(
    const int* __restrict__ edges, unsigned short* __restrict__ hb,
    unsigned short* __restrict__ lrank) {
  __shared__ int lh[NN];   // 40 KB: one key-half at a time
  int b = blockIdx.y;
  int blk = blockIdx.x;
  int t = threadIdx.x;
  const int* rows = edges + (size_t)b * 2 * EE;
  const int* cols = rows + EE;
#pragma unroll
  for (int half = 0; half < 2; ++half) {
    for (int i = t; i < NN; i += 256) lh[i] = 0;
    __syncthreads();
    for (int i = t; i < EPB; i += 256) {
      int e = blk * EPB + i;
      int row = rows[e];
      int col = cols[e];
      if ((row >= HALFN) == (half != 0)) {
        int lr = atomicAdd(&lh[col], 1);
        lrank[(size_t)b * EE + e] = (unsigned short)lr;
      }
    }
    __syncthreads();
    unsigned short* hbrow = hb + ((size_t)(b * NHB + blk)) * NK2 + half * NN;
    for (int i = t; i < NN; i += 256) hbrow[i] = (unsigned short)lh[i];
    __syncthreads();
  }
}

// ---------------------------------------------------------------------------
// 2) colscan: per key, exclusive prefix over the 64 block histograms
//    (in place) -> hb[blk][key] = #key-edges in blocks < blk; cnt[key]=total
// ---------------------------------------------------------------------------
__global__ __launch_bounds__(256) void colscan_kernel(
    unsigned short* __restrict__ hb, int* __restrict__ cnt) {
  int b = blockIdx.y;
  int k = blockIdx.x * 256 + threadIdx.x;
  if (k >= NK2) return;
  int acc = 0;
  for (int j = 0; j < NHB; ++j) {
    size_t idx = ((size_t)(b * NHB + j)) * NK2 + k;
    int v = hb[idx];
    hb[idx] = (unsigned short)acc;
    acc += v;
  }
  cnt[b * NK2 + k] = acc;
}

// ---------------------------------------------------------------------------
// 3) exclusive scan of cnt (20000 keys) -> rowstart, one block per graph
// ---------------------------------------------------------------------------
__global__ __launch_bounds__(256) void scan_kernel(
    const int* __restrict__ cnt, int* __restrict__ rowstart) {
  int b = blockIdx.x, t = threadIdx.x;
  __shared__ int s[256];
  int running = 0;
  for (int base = 0; base < NK2; base += 2048) {
    int v[8];
    int i0 = base + t * 8;
    int tsum = 0;
#pragma unroll
    for (int j = 0; j < 8; ++j) {
      v[j] = (i0 + j < NK2) ? cnt[b * NK2 + i0 + j] : 0;
      tsum += v[j];
    }
    s[t] = tsum;
    __syncthreads();
    for (int o = 1; o < 256; o <<= 1) {
      int add = (t >= o) ? s[t - o] : 0;
      __syncthreads();
      s[t] += add;
      __syncthreads();
    }
    int ex = running + s[t] - tsum;
#pragma unroll
    for (int j = 0; j < 8; ++j) {
      if (i0 + j < NK2) rowstart[b * RS + i0 + j] = ex;
      ex += v[j];
    }
    int tot = s[255];
    __syncthreads();
    running += tot;
  }
  if (t == 0) rowstart[b * RS + NK2] = running;
}

// ---------------------------------------------------------------------------
// 4) fill CSR (no atomics), 2 edges/thread:
//    pos = rowstart[key] + hb[blk][key] + lrank[e]; csr[pos]={src, bits(w)}
// ---------------------------------------------------------------------------
__global__ __launch_bounds__(256) void fill_kernel(
    const int* __restrict__ edges, const float* __restrict__ attr,
    const unsigned short* __restrict__ lrank, const unsigned short* __restrict__ hb,
    const int* __restrict__ rowstart, int2* __restrict__ csr) {
  int b = blockIdx.y;
  int e0 = (blockIdx.x * 256 + threadIdx.x) * 2;
  int blk = e0 / EPB;   // both e0, e0+1 in same hist block (EPB even)
  int2 rr = *(const int2*)(edges + (size_t)b * 2 * EE + e0);
  int2 cc = *(const int2*)(edges + (size_t)b * 2 * EE + EE + e0);
  float2 ww = *(const float2*)(attr + (size_t)b * EE + e0);
  unsigned int lr2 = *(const unsigned int*)(lrank + (size_t)b * EE + e0);
  int k0 = ((rr.x >= HALFN) ? NN : 0) + cc.x;
  int k1 = ((rr.y >= HALFN) ? NN : 0) + cc.y;
  const unsigned short* hbrow = hb + ((size_t)(b * NHB + blk)) * NK2;
  int p0 = rowstart[b * RS + k0] + (int)hbrow[k0] + (int)(lr2 & 0xffffu);
  int p1 = rowstart[b * RS + k1] + (int)hbrow[k1] + (int)(lr2 >> 16);
  csr[(size_t)b * EE + p0] = make_int2(rr.x, __float_as_int(ww.x));
  csr[(size_t)b * EE + p1] = make_int2(rr.y, __float_as_int(ww.y));
}

// ---------------------------------------------------------------------------
// 5) deg/dinv: sum both src-half segments of node n (raw w), dinv = rsqrt
// ---------------------------------------------------------------------------
__global__ __launch_bounds__(256) void deg_kernel(
    const int2* __restrict__ csr, const int* __restrict__ rowstart,
    float* __restrict__ dinv) {
  int b = blockIdx.y;
  int n = blockIdx.x * 256 + threadIdx.x;
  if (n >= NN) return;
  const int2* c = csr + (size_t)b * EE;
  float sum = 0.f;
#pragma unroll
  for (int q = 0; q < 2; ++q) {
    int key = q * NN + n;
    int s0 = rowstart[b * RS + key], s1 = rowstart[b * RS + key + 1];
    for (int i = s0; i < s1; ++i) sum += __int_as_float(c[i].y);
  }
  dinv[b * NN + n] = sum > 0.f ? rsqrtf(sum) : 0.f;
}

// ---------------------------------------------------------------------------
// 6) register-tiled GEMM, 64 rows/block, thread = 4 rows x 8 cols.
//    fused==0: x-input read directly from xsrc.
//    fused==1: x = relu((p0+p1)*dinv[row] + xbias)  (prev layer's epilogue)
// ---------------------------------------------------------------------------
__global__ __launch_bounds__(256) void gemm_kernel(
    const float* __restrict__ xsrc, const float* __restrict__ p0,
    const float* __restrict__ p1, const float* __restrict__ dinv,
    const float* __restrict__ xbias, const float* __restrict__ W,
    float* __restrict__ out, int fused) {
  __shared__ float xs[32 * 68];
  __shared__ float ws[32 * 144];
  int b = blockIdx.y;
  int row0 = blockIdx.x * 64;
  int t = threadIdx.x;
  int rg = t >> 4, cg = t & 15;
  int fc = cg * 8 + ((cg >> 2) << 2);
  float acc[4][8];
#pragma unroll
  for (int r = 0; r < 4; ++r)
#pragma unroll
    for (int j = 0; j < 8; ++j) acc[r][j] = 0.f;
  size_t gbase = (size_t)b * NN * HH;

  for (int k0 = 0; k0 < HH; k0 += 32) {
#pragma unroll
    for (int i = 0; i < 2; ++i) {
      int idx = t + i * 256;          // 0..511
      int rl = idx >> 3, kq = idx & 7;
      int row = row0 + rl;
      float4 v = make_float4(0.f, 0.f, 0.f, 0.f);
      if (row < NN) {
        size_t o = gbase + (size_t)row * HH + k0 + kq * 4;
        if (fused) {
          float4 u0 = *(const float4*)(p0 + o);
          float4 u1 = *(const float4*)(p1 + o);
          float dn = dinv[b * NN + row];
          float4 bb = *(const float4*)(xbias + k0 + kq * 4);
          v.x = fmaxf((u0.x + u1.x) * dn + bb.x, 0.f);
          v.y = fmaxf((u0.y + u1.y) * dn + bb.y, 0.f);
          v.z = fmaxf((u0.z + u1.z) * dn + bb.z, 0.f);
          v.w = fmaxf((u0.w + u1.w) * dn + bb.w, 0.f);
        } else {
          v = *(const float4*)(xsrc + o);
        }
      }
      xs[(kq * 4 + 0) * 68 + rl] = v.x;
      xs[(kq * 4 + 1) * 68 + rl] = v.y;
      xs[(kq * 4 + 2) * 68 + rl] = v.z;
      xs[(kq * 4 + 3) * 68 + rl] = v.w;
    }
#pragma unroll
    for (int i = 0; i < 4; ++i) {
      int idx = t + i * 256;          // 0..1023
      int kk = idx >> 5, c = (idx & 31) * 4;
      float4 v = *(const float4*)(W + (size_t)(k0 + kk) * HH + c);
      int f = c + ((c >> 5) << 2);
      *(float4*)&ws[kk * 144 + f] = v;
    }
    __syncthreads();
#pragma unroll 4
    for (int k = 0; k < 32; ++k) {
      float4 xv = *(const float4*)&xs[k * 68 + rg * 4];
      float4 w0 = *(const float4*)&ws[k * 144 + fc];
      float4 w1 = *(const float4*)&ws[k * 144 + fc + 4];
      const float* xp = (const float*)&xv;
#pragma unroll
      for (int r = 0; r < 4; ++r) {
        acc[r][0] += xp[r] * w0.x; acc[r][1] += xp[r] * w0.y;
        acc[r][2] += xp[r] * w0.z; acc[r][3] += xp[r] * w0.w;
        acc[r][4] += xp[r] * w1.x; acc[r][5] += xp[r] * w1.y;
        acc[r][6] += xp[r] * w1.z; acc[r][7] += xp[r] * w1.w;
      }
    }
    __syncthreads();
  }
#pragma unroll
  for (int r = 0; r < 4; ++r) {
    int row = row0 + rg * 4 + r;
    if (row < NN) {
      float* og = out + gbase + (size_t)row * HH + cg * 8;
      *(float4*)og = make_float4(acc[r][0], acc[r][1], acc[r][2], acc[r][3]);
      *(float4*)(og + 4) = make_float4(acc[r][4], acc[r][5], acc[r][6], acc[r][7]);
    }
  }
}

// ---------------------------------------------------------------------------
// 7) aggregation, ONE launch per layer. Group g=bid&7 -> (b=g>>1, q=g&1);
//    group writes partial pq[b][n] for ALL n (no inter-phase dependency),
//    gathering only xw rows of src-half q (2.56 MB, XCD-L2-resident).
// ---------------------------------------------------------------------------
__global__ __launch_bounds__(256) void agg_kernel(
    const float* __restrict__ xw, const int2* __restrict__ csr,
    const int* __restrict__ rowstart, const float* __restrict__ dinv,
    float* __restrict__ p0g, float* __restrict__ p1g) {
  int g = blockIdx.x & 7;
  int b = g >> 1;
  int q = g & 1;
  int chunk = blockIdx.x >> 3;        // 0..1249
  int half = (threadIdx.x >> 5) & 1;
  int n = chunk * 8 + (threadIdx.x >> 6) * 2 + half;
  int sl = threadIdx.x & 31;
  int key = q * NN + n;
  int s0 = rowstart[b * RS + key], s1 = rowstart[b * RS + key + 1];
  const float* xwg = xw + (size_t)b * NN * HH;
  const float* dv = dinv + b * NN;
  const int2* c = csr + (size_t)b * EE;
  float4 a0 = make_float4(0.f, 0.f, 0.f, 0.f);
  float4 a1 = make_float4(0.f, 0.f, 0.f, 0.f);
  float4 a2 = make_float4(0.f, 0.f, 0.f, 0.f);
  float4 a3 = make_float4(0.f, 0.f, 0.f, 0.f);
  int i = s0;
  for (; i + 4 <= s1; i += 4) {
    int2 e0 = c[i];
    int2 e1 = c[i + 1];
    int2 e2 = c[i + 2];
    int2 e3 = c[i + 3];
    float w0 = __int_as_float(e0.y) * dv[e0.x];
    float w1 = __int_as_float(e1.y) * dv[e1.x];
    float w2 = __int_as_float(e2.y) * dv[e2.x];
    float w3 = __int_as_float(e3.y) * dv[e3.x];
    float4 v0 = *(const float4*)(xwg + (size_t)e0.x * HH + sl * 4);
    float4 v1 = *(const float4*)(xwg + (size_t)e1.x * HH + sl * 4);
    float4 v2 = *(const float4*)(xwg + (size_t)e2.x * HH + sl * 4);
    float4 v3 = *(const float4*)(xwg + (size_t)e3.x * HH + sl * 4);
    a0.x += w0 * v0.x; a0.y += w0 * v0.y; a0.z += w0 * v0.z; a0.w += w0 * v0.w;
    a1.x += w1 * v1.x; a1.y += w1 * v1.y; a1.z += w1 * v1.z; a1.w += w1 * v1.w;
    a2.x += w2 * v2.x; a2.y += w2 * v2.y; a2.z += w2 * v2.z; a2.w += w2 * v2.w;
    a3.x += w3 * v3.x; a3.y += w3 * v3.y; a3.z += w3 * v3.z; a3.w += w3 * v3.w;
  }
  for (; i < s1; ++i) {
    int2 e0 = c[i];
    float w0 = __int_as_float(e0.y) * dv[e0.x];
    float4 v0 = *(const float4*)(xwg + (size_t)e0.x * HH + sl * 4);
    a0.x += w0 * v0.x; a0.y += w0 * v0.y; a0.z += w0 * v0.z; a0.w += w0 * v0.w;
  }
  a0.x += a1.x + a2.x + a3.x;
  a0.y += a1.y + a2.y + a3.y;
  a0.z += a1.z + a2.z + a3.z;
  a0.w += a1.w + a2.w + a3.w;
  float* pq = (q == 0) ? p0g : p1g;
  *(float4*)(pq + ((size_t)b * NN + n) * HH + sl * 4) = a0;
}

// ---------------------------------------------------------------------------
// 8) readout: fused layer-3 epilogue + mean + Wl
// ---------------------------------------------------------------------------
__global__ __launch_bounds__(64) void init_out_kernel(float* out, const float* __restrict__ bl) {
  if (threadIdx.x < BB) out[threadIdx.x] = bl[0];
}

__global__ __launch_bounds__(256) void final_kernel(
    const float* __restrict__ p0g, const float* __restrict__ p1g,
    const float* __restrict__ dinv, const float* __restrict__ b3,
    const float* __restrict__ Wl, float* __restrict__ out) {
  int b = blockIdx.y;
  int t = threadIdx.x;
  int f = t & 127;
  int rr = t >> 7;
  float bf = b3[f];
  const float* dv = dinv + b * NN;
  float p = 0.f;
  for (int n = blockIdx.x * 2 + rr; n < NN; n += gridDim.x * 2) {
    size_t o = ((size_t)b * NN + n) * HH + f;
    p += fmaxf((p0g[o] + p1g[o]) * dv[n] + bf, 0.f);
  }
  __shared__ float s[256];
  s[t] = p;
  __syncthreads();
  float v = 0.f;
  if (t < 128) v = (s[t] + s[t + 128]) * Wl[f];
  __syncthreads();
  s[t] = v;
  __syncthreads();
  for (int o = 64; o > 0; o >>= 1) {
    if (t < o) s[t] += s[t + o];
    __syncthreads();
  }
  if (t == 0) atomicAdd(&out[b], s[0] * (1.0f / NN));
}

// ---------------------------------------------------------------------------
extern "C" void kernel_launch(void* const* d_in, const int* in_sizes, int n_in,
                              void* d_out, int out_size, void* d_ws, size_t ws_size,
                              hipStream_t stream) {
  const float* feat = (const float*)d_in[0];
  const int* edges = (const int*)d_in[1];
  const float* attr = (const float*)d_in[2];
  const float* W1 = (const float*)d_in[3];
  const float* b1 = (const float*)d_in[4];
  const float* W2 = (const float*)d_in[5];
  const float* b2 = (const float*)d_in[6];
  const float* W3 = (const float*)d_in[7];
  const float* b3 = (const float*)d_in[8];
  const float* Wl = (const float*)d_in[9];
  const float* bl = (const float*)d_in[10];
  float* out = (float*)d_out;

  char* ws = (char*)d_ws;
  size_t off = 0;
  auto alloc = [&](size_t bytes) {
    size_t o = off;
    off = (off + bytes + 255) & ~(size_t)255;
    return o;
  };
  int*   cnt      = (int*)  (ws + alloc((size_t)BB * NK2 * 4));        // 320 KB
  int*   rowstart = (int*)  (ws + alloc((size_t)BB * RS * 4));         // 320 KB
  int2*  csr      = (int2*) (ws + alloc((size_t)BB * EE * 8));         // 10.24 MB
  float* xw       = (float*)(ws + alloc((size_t)BB * NN * HH * 4));    // 20.48 MB
  float* p0       = (float*)(ws + alloc((size_t)BB * NN * HH * 4));    // 20.48 MB
  float* p1       = (float*)(ws + alloc((size_t)BB * NN * HH * 4));    // 20.48 MB
  // transient aliases (dead before gemm/agg touch xw/p0):
  unsigned short* lrank = (unsigned short*)xw;  // 2.56 MB, live hist..fill
  unsigned short* hb    = (unsigned short*)p0;  // 10.24 MB, live hist..fill
  float* dinv = (float*)cnt;                    // live deg..end

  dim3 hgrid(NHB, BB);
  hist_kernel<<<hgrid, 256, 0, stream>>>(edges, hb, lrank);
  colscan_kernel<<<dim3((NK2 + 255) / 256, BB), 256, 0, stream>>>(hb, cnt);
  scan_kernel<<<BB, 256, 0, stream>>>(cnt, rowstart);
  dim3 egrid2(EE / 512, BB);   // 2 edges/thread
  fill_kernel<<<egrid2, 256, 0, stream>>>(edges, attr, lrank, hb, rowstart, csr);
  deg_kernel<<<dim3((NN + 255) / 256, BB), 256, 0, stream>>>(csr, rowstart, dinv);

  dim3 ggrid((NN + 63) / 64, BB);
  int agrid = 8 * (NN / 8);   // 8 XCD-groups x 1250 chunks (8 nodes/block)

  // layer 1: xw = feat@W1 ; p0/p1 partials
  gemm_kernel<<<ggrid, 256, 0, stream>>>(feat, nullptr, nullptr, nullptr, nullptr, W1, xw, 0);
  agg_kernel<<<agrid, 256, 0, stream>>>(xw, csr, rowstart, dinv, p0, p1);
  // layer 2: xw = relu((p0+p1)*dn+b1)@W2 ; partials
  gemm_kernel<<<ggrid, 256, 0, stream>>>(nullptr, p0, p1, dinv, b1, W2, xw, 1);
  agg_kernel<<<agrid, 256, 0, stream>>>(xw, csr, rowstart, dinv, p0, p1);
  // layer 3
  gemm_kernel<<<ggrid, 256, 0, stream>>>(nullptr, p0, p1, dinv, b2, W3, xw, 1);
  agg_kernel<<<agrid, 256, 0, stream>>>(xw, csr, rowstart, dinv, p0, p1);

  init_out_kernel<<<1, 64, 0, stream>>>(out, bl);
  final_kernel<<<dim3(64, BB), 256, 0, stream>>>(p0, p1, dinv, b3, Wl, out);
}